// Round 9
// baseline (377.698 us; speedup 1.0000x reference)
//
#include <hip/hip_runtime.h>
#include <hip/hip_bf16.h>

// GCN 2-layer: out = log_softmax(GCN2(relu(GCN1(x))))
// Round 16: gemm1 tile 128->64 rows (256 thr, 4 waves). R13's 96 KB LDS
// meant 1 block/CU: during barrier+MFMA phases no loads in flight (duty-
// cycle hole). 80 KB (64 W + 2x8 A dbuf) -> exactly 2 blocks/CU; blocks
// alternate staging/compute -> loads always in flight. Same coalesced
// swizzled staging math (2 short8 slots/thread/chunk). W re-staged per 64
// rows (+100 MB L2-resident reads ~ 3us, noise).
// agg1f (R15 fused, 94% of gather floor), agg2, sort byte-frozen.

#define N_NODES 100000
#define F_IN 256
#define F_MID 128
#define F_OUT 64

#define BSHIFT 8                      // 256 nodes per bucket
#define BNODES 256
#define NBUCKETS ((N_NODES + BNODES - 1) / BNODES)   // 391
#define BCAP 6144                     // mean 4096, sigma ~64 -> +32 sigma
#define EPB 4096                      // edges per scatter block

typedef __attribute__((ext_vector_type(8))) short short8;
typedef __attribute__((ext_vector_type(4))) float f32x4;

__device__ inline ushort bf16_rne(float f) {
    uint u = __float_as_uint(f);
    u += 0x7FFF + ((u >> 16) & 1);
    return (ushort)(u >> 16);
}
__device__ inline float lo16(uint r) { return __uint_as_float(r << 16); }
__device__ inline float hi16(uint r) { return __uint_as_float(r & 0xffff0000u); }
__device__ inline uint pack_bf2(float a, float b) {
    return (uint)bf16_rne(a) | ((uint)bf16_rne(b) << 16);
}

// ---------------- two-level bucket sort ----------------

// S1: block-binned scatter. packed = (dst&255)<<17 | src  (25 bits)
__global__ __launch_bounds__(256)
void bucket_scatter_kernel(const int* __restrict__ src, const int* __restrict__ dst,
                           int* __restrict__ bcur, uint* __restrict__ ebuf, int E) {
    __shared__ int curL[NBUCKETS];
    int t = threadIdx.x;
    int e0 = blockIdx.x * EPB;
    int e1 = e0 + EPB; if (e1 > E) e1 = E;

    for (int i = t; i < NBUCKETS; i += 256) curL[i] = 0;
    __syncthreads();
    for (int i = e0 + t; i < e1; i += 256) atomicAdd(&curL[dst[i] >> BSHIFT], 1);
    __syncthreads();
    for (int i = t; i < NBUCKETS; i += 256) {
        int h = curL[i];
        curL[i] = h ? atomicAdd(&bcur[i], h) : 0;
    }
    __syncthreads();
    for (int i = e0 + t; i < e1; i += 256) {
        int d = dst[i], s = src[i];
        int b = d >> BSHIFT;
        int pos = atomicAdd(&curL[b], 1);
        if (pos < BCAP) ebuf[(size_t)b * BCAP + pos] = ((uint)(d & (BNODES - 1)) << 17) | (uint)s;
    }
}

// S2: per-bucket counting sort; emits ssrc + rs + cnt + dinv.
__global__ __launch_bounds__(256)
void bucket_sort_kernel(const uint* __restrict__ ebuf, const int* __restrict__ bcur,
                        int* __restrict__ ssrc, int* __restrict__ rs, int* __restrict__ cnt,
                        float* __restrict__ dinv, int n) {
    __shared__ uint eL[BCAP];          // 24 KB
    __shared__ int hist[BNODES], ps[BNODES];
    int b = blockIdx.x, t = threadIdx.x;
    int nb = bcur[b];
    if (nb > BCAP) nb = BCAP;
    for (int i = t; i < nb; i += 256) eL[i] = ebuf[(size_t)b * BCAP + i];
    hist[t] = 0;
    __syncthreads();
    for (int i = t; i < nb; i += 256) atomicAdd(&hist[eL[i] >> 17], 1);
    __syncthreads();
    ps[t] = hist[t];
    __syncthreads();
#pragma unroll
    for (int off = 1; off < BNODES; off <<= 1) {
        int v = (t >= off) ? ps[t - off] : 0;
        __syncthreads();
        ps[t] += v;
        __syncthreads();
    }
    int excl = ps[t] - hist[t];
    int node = b * BNODES + t;
    if (node < n) {
        rs[node] = b * BCAP + excl;
        cnt[node] = hist[t];
        dinv[node] = 1.0f / sqrtf((float)hist[t] + 1.0f);
    }
    __syncthreads();
    ps[t] = excl;                      // reuse as running cursor
    __syncthreads();
    for (int i = t; i < nb; i += 256) {
        uint e = eL[i];
        int d = e >> 17;
        int p = atomicAdd(&ps[d], 1);
        ssrc[(size_t)b * BCAP + p] = (int)(e & 0x1FFFF);
    }
}

// ---------------- weight prep: fragment-ordered bf16 ----------------
// mfma_f32_16x16x32_bf16 B-frag: lane holds B[k=(lane>>4)*8+j][n=lane&15].
__global__ __launch_bounds__(256)
void wprep_kernel(const float* __restrict__ W1, const float* __restrict__ W2,
                  short8* __restrict__ W1f, short8* __restrict__ W2f) {
    int b = blockIdx.x;
    if (b < 16) {
        int f = b * 256 + threadIdx.x;
        int k0 = f >> 9, nt = (f >> 6) & 7, ln = f & 63;
        int kbase = k0 * 32 + (ln >> 4) * 8;
        int n = nt * 16 + (ln & 15);
        short8 fr;
#pragma unroll
        for (int j = 0; j < 8; ++j) fr[j] = (short)bf16_rne(W1[(kbase + j) * F_MID + n]);
        W1f[f] = fr;
    } else {
        int f = (b - 16) * 256 + threadIdx.x;
        int k0 = f >> 8, nt = (f >> 6) & 3, ln = f & 63;
        int kbase = k0 * 32 + (ln >> 4) * 8;
        int n = nt * 16 + (ln & 15);
        short8 fr;
#pragma unroll
        for (int j = 0; j < 8; ++j) fr[j] = (short)bf16_rne(W2[(kbase + j) * F_OUT + n]);
        W2f[f] = fr;
    }
}

// ---------------- MFMA GEMM 1 ----------------
// A: lane holds A[m=lane&15][k=(lane>>4)*8+j]; C/D: col=lane&15, row=(lane>>4)*4+reg.

// h1s[M,128](bf16) = dinv[m] * (x[M,256](fp32) @ W1bf16)
// 4 waves x 16 rows = 64-row tile; 80 KB LDS -> 2 blocks/CU so staging of
// one block overlaps compute of the other. A staged per 64-col K-chunk as
// bf16 in A-frag order (coalesced, convert during staging, XOR-swizzled).
__global__ __launch_bounds__(256, 2)
void gemm1_kernel(const float* __restrict__ A, const short8* __restrict__ Wf,
                  const float* __restrict__ dinv, ushort* __restrict__ C,
                  int M) {
    __shared__ short8 BsF[4096];          // 64 KB: W1 fragments
    __shared__ ushort Abuf[2][64 * 64];   // 2 x 8 KB: bf16 A chunks
    int tid = threadIdx.x;
    int lane = tid & 63, w = tid >> 6;    // w in 0..3
    int m0 = blockIdx.x * 64;

    // per-thread staging slots: o = tid*2 + {0,1} in [0,512)
    //   row = o>>3 (0..63), cl = o&7 (dest slot), cg = cl ^ (row&7)
    //   src = A[(m0+row)*256 + kc*64 + cg*8 .. +8)   (32 B)
    //   dst = Abuf[b][o*8 .. +8)                      (16 B)
    int o0 = tid * 2;
    int srow = o0 >> 3;                   // both slots share the row
    int gr = m0 + srow; if (gr >= M) gr = m0;   // clamp (garbage rows unused)
    int cl0 = o0 & 7, cl1 = cl0 + 1;
    int cg0 = cl0 ^ (srow & 7), cg1 = cl1 ^ (srow & 7);
    const float* arow = &A[(size_t)gr * F_IN];

    float4 rv[2][2];
    rv[0][0] = ((const float4*)(arow + cg0 * 8))[0];
    rv[0][1] = ((const float4*)(arow + cg0 * 8))[1];
    rv[1][0] = ((const float4*)(arow + cg1 * 8))[0];
    rv[1][1] = ((const float4*)(arow + cg1 * 8))[1];

    for (int f = tid; f < 4096; f += 256) BsF[f] = Wf[f];

    {
        short8 pk;
        pk[0] = (short)bf16_rne(rv[0][0].x); pk[1] = (short)bf16_rne(rv[0][0].y);
        pk[2] = (short)bf16_rne(rv[0][0].z); pk[3] = (short)bf16_rne(rv[0][0].w);
        pk[4] = (short)bf16_rne(rv[0][1].x); pk[5] = (short)bf16_rne(rv[0][1].y);
        pk[6] = (short)bf16_rne(rv[0][1].z); pk[7] = (short)bf16_rne(rv[0][1].w);
        *(short8*)&Abuf[0][o0 * 8] = pk;
        pk[0] = (short)bf16_rne(rv[1][0].x); pk[1] = (short)bf16_rne(rv[1][0].y);
        pk[2] = (short)bf16_rne(rv[1][0].z); pk[3] = (short)bf16_rne(rv[1][0].w);
        pk[4] = (short)bf16_rne(rv[1][1].x); pk[5] = (short)bf16_rne(rv[1][1].y);
        pk[6] = (short)bf16_rne(rv[1][1].z); pk[7] = (short)bf16_rne(rv[1][1].w);
        *(short8*)&Abuf[0][(o0 + 1) * 8] = pk;
    }
    __syncthreads();

    f32x4 acc[8];
#pragma unroll
    for (int nt = 0; nt < 8; ++nt) acc[nt] = (f32x4){0.f, 0.f, 0.f, 0.f};

    int arow16 = w * 16 + (lane & 15);    // this lane's A-frag row in tile
    int asw = arow16 & 7;
    int abase = arow16 * 8;               // slot base for that row

#pragma unroll
    for (int kc = 0; kc < 4; ++kc) {
        int b = kc & 1;
        if (kc < 3) {
            const float* s0 = arow + (kc + 1) * 64 + cg0 * 8;
            const float* s1 = arow + (kc + 1) * 64 + cg1 * 8;
            rv[0][0] = ((const float4*)s0)[0];
            rv[0][1] = ((const float4*)s0)[1];
            rv[1][0] = ((const float4*)s1)[0];
            rv[1][1] = ((const float4*)s1)[1];
            asm volatile("" ::: "memory");
        }
#pragma unroll
        for (int kk = 0; kk < 2; ++kk) {
            int k0 = kc * 2 + kk;
            int c = kk * 4 + (lane >> 4);
            short8 af = *(const short8*)&Abuf[b][(abase + (c ^ asw)) * 8];
#pragma unroll
            for (int nt = 0; nt < 8; ++nt) {
                short8 bfr = BsF[(k0 * 8 + nt) * 64 + lane];
                acc[nt] = __builtin_amdgcn_mfma_f32_16x16x32_bf16(af, bfr, acc[nt], 0, 0, 0);
            }
        }
        if (kc < 3) {
            short8 pk;
            pk[0] = (short)bf16_rne(rv[0][0].x); pk[1] = (short)bf16_rne(rv[0][0].y);
            pk[2] = (short)bf16_rne(rv[0][0].z); pk[3] = (short)bf16_rne(rv[0][0].w);
            pk[4] = (short)bf16_rne(rv[0][1].x); pk[5] = (short)bf16_rne(rv[0][1].y);
            pk[6] = (short)bf16_rne(rv[0][1].z); pk[7] = (short)bf16_rne(rv[0][1].w);
            *(short8*)&Abuf[b ^ 1][o0 * 8] = pk;
            pk[0] = (short)bf16_rne(rv[1][0].x); pk[1] = (short)bf16_rne(rv[1][0].y);
            pk[2] = (short)bf16_rne(rv[1][0].z); pk[3] = (short)bf16_rne(rv[1][0].w);
            pk[4] = (short)bf16_rne(rv[1][1].x); pk[5] = (short)bf16_rne(rv[1][1].y);
            pk[6] = (short)bf16_rne(rv[1][1].z); pk[7] = (short)bf16_rne(rv[1][1].w);
            *(short8*)&Abuf[b ^ 1][(o0 + 1) * 8] = pk;
        }
        __syncthreads();
    }

#pragma unroll
    for (int i = 0; i < 4; ++i) {
        int r = blockIdx.x * 64 + w * 16 + (lane >> 4) * 4 + i;
        if (r < M) {
            float dv = dinv[r];
#pragma unroll
            for (int nt = 0; nt < 8; ++nt)
                C[(size_t)r * F_MID + nt * 16 + (lane & 15)] = bf16_rne(dv * acc[nt][i]);
        }
    }
}

// ---------------- fused aggregation-1 + gemm2 ----------------
// Block = 256 threads = 4 waves, 16 nodes. Phase 1: wave w serially
// aggregates nodes base+w*4+i (quarter q handles edges base+4j+q, x4
// unroll), applies dinv/b1/relu, stages the 128-col bf16 row into LDS
// (stride 136 shorts -> 2-way banks). Phase 2: wave w computes h2 col-tile
// nt=w for all 16 rows via 4 MFMAs: h2 = dinv * (rows @ W2).
__global__ __launch_bounds__(256)
void agg1f_kernel(const uint4* __restrict__ h, const int* __restrict__ rs,
                  const int* __restrict__ cnt, const int* __restrict__ ssrc,
                  const float* __restrict__ dinv, const float* __restrict__ bias,
                  const short8* __restrict__ W2f, ushort* __restrict__ h2, int n) {
    __shared__ __align__(16) ushort rowsL[16][136];   // 16 rows x 128 bf16 + pad
    int w = threadIdx.x >> 6, lane = threadIdx.x & 63;
    int q = lane >> 4, c16 = lane & 15;
    int nbase = blockIdx.x * 16;
    const float4* b4 = (const float4*)bias;
    float4 b0 = b4[c16 * 2], b1v = b4[c16 * 2 + 1];

#pragma unroll
    for (int i = 0; i < 4; ++i) {
        int node = nbase + w * 4 + i;
        bool nOk = (node < n);
        int start = nOk ? rs[node] : 0;
        int c = nOk ? cnt[node] : 0;
        float dn = nOk ? dinv[node] : 0.f;
        float a[8];
#pragma unroll
        for (int k = 0; k < 8; ++k) a[k] = 0.f;

        for (int base = 0; base < c; base += 16) {
            bool p[4];
            int s[4];
            uint4 r[4];
#pragma unroll
            for (int j = 0; j < 4; ++j) {
                int e = base + j * 4 + q;
                p[j] = e < c;
                if (p[j]) s[j] = ssrc[start + e];
            }
#pragma unroll
            for (int j = 0; j < 4; ++j)
                if (p[j]) r[j] = h[(size_t)s[j] * 16 + c16];
#pragma unroll
            for (int j = 0; j < 4; ++j) {
                if (p[j]) {
                    a[0] += lo16(r[j].x); a[1] += hi16(r[j].x);
                    a[2] += lo16(r[j].y); a[3] += hi16(r[j].y);
                    a[4] += lo16(r[j].z); a[5] += hi16(r[j].z);
                    a[6] += lo16(r[j].w); a[7] += hi16(r[j].w);
                }
            }
        }
#pragma unroll
        for (int k = 0; k < 8; ++k) {
            a[k] += __shfl_xor(a[k], 16);
            a[k] += __shfl_xor(a[k], 32);
        }
        if (q == 0) {
            short8 pk;
            if (nOk) {
                uint4 sr = h[(size_t)node * 16 + c16];
                float o0 = fmaxf(fmaf(dn, a[0] + lo16(sr.x), b0.x), 0.f);
                float o1 = fmaxf(fmaf(dn, a[1] + hi16(sr.x), b0.y), 0.f);
                float o2 = fmaxf(fmaf(dn, a[2] + lo16(sr.y), b0.z), 0.f);
                float o3 = fmaxf(fmaf(dn, a[3] + hi16(sr.y), b0.w), 0.f);
                float o4 = fmaxf(fmaf(dn, a[4] + lo16(sr.z), b1v.x), 0.f);
                float o5 = fmaxf(fmaf(dn, a[5] + hi16(sr.z), b1v.y), 0.f);
                float o6 = fmaxf(fmaf(dn, a[6] + lo16(sr.w), b1v.z), 0.f);
                float o7 = fmaxf(fmaf(dn, a[7] + hi16(sr.w), b1v.w), 0.f);
                pk[0] = (short)bf16_rne(o0); pk[1] = (short)bf16_rne(o1);
                pk[2] = (short)bf16_rne(o2); pk[3] = (short)bf16_rne(o3);
                pk[4] = (short)bf16_rne(o4); pk[5] = (short)bf16_rne(o5);
                pk[6] = (short)bf16_rne(o6); pk[7] = (short)bf16_rne(o7);
            } else {
                pk = (short8){0, 0, 0, 0, 0, 0, 0, 0};
            }
            *(short8*)&rowsL[w * 4 + i][c16 * 8] = pk;
        }
    }
    __syncthreads();

    // phase 2: wave w -> col-tile nt=w. A: lane reads LDS row (lane&15),
    // k-slice k0*32+(lane>>4)*8; B: W2f[(k0*4+w)*64+lane] (L2-hot, 16 KB).
    f32x4 acc = (f32x4){0.f, 0.f, 0.f, 0.f};
    int ar = lane & 15;
#pragma unroll
    for (int k0 = 0; k0 < 4; ++k0) {
        short8 af = *(const short8*)&rowsL[ar][k0 * 32 + (lane >> 4) * 8];
        short8 bfr = W2f[(k0 * 4 + w) * 64 + lane];
        acc = __builtin_amdgcn_mfma_f32_16x16x32_bf16(af, bfr, acc, 0, 0, 0);
    }
#pragma unroll
    for (int i = 0; i < 4; ++i) {
        int r = (lane >> 4) * 4 + i;
        int node = nbase + r;
        if (node < n) {
            float dv = dinv[node];
            h2[(size_t)node * F_OUT + w * 16 + (lane & 15)] = bf16_rne(dv * acc[i]);
        }
    }
}

// agg2: 64-col bf16 rows (128 B), 16 lanes x uint2; x4-unrolled gather;
// fused bias + log_softmax.
__global__ __launch_bounds__(256)
void agg2_kernel(const uint2* __restrict__ h, const int* __restrict__ rs,
                 const int* __restrict__ cnt, const int* __restrict__ ssrc,
                 const float* __restrict__ dinv, const float* __restrict__ bias,
                 float4* __restrict__ out4, int n) {
    int w = threadIdx.x >> 6, lane = threadIdx.x & 63;
    int node = blockIdx.x * 4 + w;
    if (node >= n) return;
    int q = lane >> 4, c16 = lane & 15;
    int start = rs[node], c = cnt[node];
    float dn = dinv[node];
    float a[4];
#pragma unroll
    for (int i = 0; i < 4; ++i) a[i] = 0.f;

    for (int base = 0; base < c; base += 16) {
        bool p[4];
        int s[4];
        uint2 r[4];
#pragma unroll
        for (int j = 0; j < 4; ++j) {
            int e = base + j * 4 + q;
            p[j] = e < c;
            if (p[j]) s[j] = ssrc[start + e];
        }
#pragma unroll
        for (int j = 0; j < 4; ++j)
            if (p[j]) r[j] = h[(size_t)s[j] * 16 + c16];
#pragma unroll
        for (int j = 0; j < 4; ++j) {
            if (p[j]) {
                a[0] += lo16(r[j].x); a[1] += hi16(r[j].x);
                a[2] += lo16(r[j].y); a[3] += hi16(r[j].y);
            }
        }
    }
#pragma unroll
    for (int i = 0; i < 4; ++i) {
        a[i] += __shfl_xor(a[i], 16);
        a[i] += __shfl_xor(a[i], 32);
    }
    uint2 sr = h[(size_t)node * 16 + c16];
    float4 bv = ((const float4*)bias)[c16];
    float v0 = fmaf(dn, a[0] + lo16(sr.x), bv.x);
    float v1 = fmaf(dn, a[1] + hi16(sr.x), bv.y);
    float v2 = fmaf(dn, a[2] + lo16(sr.y), bv.z);
    float v3 = fmaf(dn, a[3] + hi16(sr.y), bv.w);
    float m = fmaxf(fmaxf(v0, v1), fmaxf(v2, v3));
#pragma unroll
    for (int off = 1; off < 16; off <<= 1) m = fmaxf(m, __shfl_xor(m, off));
    float ssum = expf(v0 - m) + expf(v1 - m) + expf(v2 - m) + expf(v3 - m);
#pragma unroll
    for (int off = 1; off < 16; off <<= 1) ssum += __shfl_xor(ssum, off);
    float lg = m + logf(ssum);
    if (q == 0) out4[(size_t)node * 16 + c16] = make_float4(v0 - lg, v1 - lg, v2 - lg, v3 - lg);
}

// ---------------- launch ----------------

extern "C" void kernel_launch(void* const* d_in, const int* in_sizes, int n_in,
                              void* d_out, int out_size, void* d_ws, size_t ws_size,
                              hipStream_t stream) {
    const float* x  = (const float*)d_in[0];
    const int*   ei = (const int*)d_in[1];
    const float* W1 = (const float*)d_in[2];
    const float* b1 = (const float*)d_in[3];
    const float* W2 = (const float*)d_in[4];
    const float* b2 = (const float*)d_in[5];
    float* out = (float*)d_out;

    const int N = N_NODES;
    const int E = in_sizes[1] / 2;
    const int* src = ei;
    const int* dst = ei + E;

    char* ws = (char*)d_ws;
    size_t off = 0;
    auto alloc = [&](size_t bytes) {
        char* p = ws + off;
        off = (off + bytes + 255) & ~(size_t)255;
        return p;
    };
    int*    bcur   = (int*)alloc(NBUCKETS * 4);
    int*    rs     = (int*)alloc(N * 4);
    int*    cnt    = (int*)alloc(N * 4);
    float*  dinv   = (float*)alloc(N * 4);
    short8* W1f    = (short8*)alloc(4096 * 16);
    short8* W2f    = (short8*)alloc(1024 * 16);
    uint*   ebuf   = (uint*)alloc((size_t)NBUCKETS * BCAP * 4);   // 9.6 MB
    int*    ssrc   = (int*)alloc((size_t)NBUCKETS * BCAP * 4);    // 9.6 MB
    uint*   h1     = (uint*)alloc((size_t)N * 64 * 4);            // 128 bf16/row
    ushort* h2     = (ushort*)alloc((size_t)N * 64 * 2);          // 64 bf16/row

    const int nScatBlocks = (E + EPB - 1) / EPB;         // 391
    const int nAgg1Blocks = (N + 15) / 16;               // 6250
    const int nAgg2Blocks = (N + 3) / 4;
    const int nTiles64    = (N + 63) / 64;               // 1563

    hipMemsetAsync(bcur, 0, NBUCKETS * 4, stream);
    wprep_kernel<<<20, 256, 0, stream>>>(W1, W2, W1f, W2f);

    bucket_scatter_kernel<<<nScatBlocks, 256, 0, stream>>>(src, dst, bcur, ebuf, E);
    bucket_sort_kernel<<<NBUCKETS, 256, 0, stream>>>(ebuf, bcur, ssrc, rs, cnt, dinv, N);

    gemm1_kernel<<<nTiles64, 256, 0, stream>>>(x, W1f, dinv, (ushort*)h1, N);
    agg1f_kernel<<<nAgg1Blocks, 256, 0, stream>>>((const uint4*)h1, rs, cnt, ssrc, dinv, b1,
                                                  W2f, h2, N);
    agg2_kernel<<<nAgg2Blocks, 256, 0, stream>>>((const uint2*)h2, rs, cnt, ssrc, dinv, b2,
                                                 (float4*)out, N);
}

// Round 10
// 359.253 us; speedup vs baseline: 1.0513x; 1.0513x over previous
//
#include <hip/hip_runtime.h>
#include <hip/hip_bf16.h>

// GCN 2-layer: out = log_softmax(GCN2(relu(GCN1(x))))
// Round 17: (1) gemm1 reverted to R13 128-row tile (R16's 64-row tile
// regressed -10us: halved per-block MFMA work but kept full 64KB W-stage
// -> amortization loss beat the duty-cycle win). (2) bucket_scatter v2:
// block-local counting sort by bucket in LDS (scan over 512-padded bins),
// then chunked copy-out -- each bucket's ~10 edges land at consecutive
// global addresses (coalesced bursts) instead of 1.6M random 4-B writes.
// (3) bucket_sort v2: sorted bucket built in LDS (sLoc) then streamed to
// ssrc coalesced -- removes the other 1.6M random 4-B writes.
// agg1f (at its once-per-XCD L2-fill floor, 189MB), agg2, wprep frozen.

#define N_NODES 100000
#define F_IN 256
#define F_MID 128
#define F_OUT 64

#define BSHIFT 8                      // 256 nodes per bucket
#define BNODES 256
#define NBUCKETS ((N_NODES + BNODES - 1) / BNODES)   // 391
#define BCAP 6144                     // mean 4096, sigma ~64 -> +32 sigma
#define EPB 4096                      // edges per scatter block

typedef __attribute__((ext_vector_type(8))) short short8;
typedef __attribute__((ext_vector_type(4))) float f32x4;

__device__ inline ushort bf16_rne(float f) {
    uint u = __float_as_uint(f);
    u += 0x7FFF + ((u >> 16) & 1);
    return (ushort)(u >> 16);
}
__device__ inline float lo16(uint r) { return __uint_as_float(r << 16); }
__device__ inline float hi16(uint r) { return __uint_as_float(r & 0xffff0000u); }
__device__ inline uint pack_bf2(float a, float b) {
    return (uint)bf16_rne(a) | ((uint)bf16_rne(b) << 16);
}

// ---------------- two-level bucket sort ----------------

// S1 v2: block-local counting sort by bucket, chunked coalesced copy-out.
// packed = (dst&255)<<17 | src  (25 bits)
__global__ __launch_bounds__(256)
void bucket_scatter_kernel(const int* __restrict__ src, const int* __restrict__ dst,
                           int* __restrict__ bcur, uint* __restrict__ ebuf, int E) {
    __shared__ int hist[512], ps[512], cur[512];
    __shared__ int base[NBUCKETS];
    __shared__ uint   eLoc[EPB];      // 16 KB packed edges, bucket-grouped
    __shared__ ushort bLoc[EPB];      // 8 KB bucket id per local slot
    int t = threadIdx.x;
    int e0 = blockIdx.x * EPB;
    int e1 = e0 + EPB; if (e1 > E) e1 = E;
    int ne = e1 - e0;

    for (int i = t; i < 512; i += 256) hist[i] = 0;
    __syncthreads();
    for (int i = t; i < ne; i += 256) atomicAdd(&hist[dst[e0 + i] >> BSHIFT], 1);
    __syncthreads();
    // inclusive Hillis-Steele over 512 bins, 2 elems/thread
    ps[t] = hist[t]; ps[t + 256] = hist[t + 256];
    __syncthreads();
#pragma unroll
    for (int off = 1; off < 512; off <<= 1) {
        int i0 = t, i1 = t + 256;
        int v0 = (i0 >= off) ? ps[i0 - off] : 0;
        int v1 = (i1 >= off) ? ps[i1 - off] : 0;
        __syncthreads();
        ps[i0] += v0; ps[i1] += v1;
        __syncthreads();
    }
    // ps -> exclusive; cur = running cursor
    {
        int ex0 = ps[t] - hist[t];
        int ex1 = ps[t + 256] - hist[t + 256];
        __syncthreads();
        ps[t] = ex0; ps[t + 256] = ex1;
        cur[t] = ex0; cur[t + 256] = ex1;
    }
    __syncthreads();
    // local scatter into LDS (bucket-grouped)
    for (int i = t; i < ne; i += 256) {
        int d = dst[e0 + i], s = src[e0 + i];
        int b = d >> BSHIFT;
        int p = atomicAdd(&cur[b], 1);
        eLoc[p] = ((uint)(d & (BNODES - 1)) << 17) | (uint)s;
        bLoc[p] = (ushort)b;
    }
    __syncthreads();
    // reserve global ranges (one atomic per non-empty bucket)
    for (int b = t; b < NBUCKETS; b += 256) {
        int h = hist[b];
        base[b] = h ? atomicAdd(&bcur[b], h) : 0;
    }
    __syncthreads();
    // chunked copy-out: consecutive local slots of a bucket -> consecutive
    // global addresses (coalesced ~40-B bursts)
    for (int i = t; i < ne; i += 256) {
        int b = bLoc[i];
        int d = base[b] + (i - ps[b]);
        if (d < BCAP) ebuf[(size_t)b * BCAP + d] = eLoc[i];
    }
}

// S2 v2: per-bucket counting sort; sorted list built in LDS then streamed
// out coalesced. Emits ssrc + rs + cnt + dinv.
__global__ __launch_bounds__(256)
void bucket_sort_kernel(const uint* __restrict__ ebuf, const int* __restrict__ bcur,
                        int* __restrict__ ssrc, int* __restrict__ rs, int* __restrict__ cnt,
                        float* __restrict__ dinv, int n) {
    __shared__ uint eL[BCAP];          // 24 KB
    __shared__ int  sLoc[BCAP];        // 24 KB sorted srcs
    __shared__ int hist[BNODES], ps[BNODES];
    int b = blockIdx.x, t = threadIdx.x;
    int nb = bcur[b];
    if (nb > BCAP) nb = BCAP;
    for (int i = t; i < nb; i += 256) eL[i] = ebuf[(size_t)b * BCAP + i];
    hist[t] = 0;
    __syncthreads();
    for (int i = t; i < nb; i += 256) atomicAdd(&hist[eL[i] >> 17], 1);
    __syncthreads();
    ps[t] = hist[t];
    __syncthreads();
#pragma unroll
    for (int off = 1; off < BNODES; off <<= 1) {
        int v = (t >= off) ? ps[t - off] : 0;
        __syncthreads();
        ps[t] += v;
        __syncthreads();
    }
    int excl = ps[t] - hist[t];
    int node = b * BNODES + t;
    if (node < n) {
        rs[node] = b * BCAP + excl;
        cnt[node] = hist[t];
        dinv[node] = 1.0f / sqrtf((float)hist[t] + 1.0f);
    }
    __syncthreads();
    ps[t] = excl;                      // reuse as running cursor
    __syncthreads();
    for (int i = t; i < nb; i += 256) {
        uint e = eL[i];
        int d = e >> 17;
        int p = atomicAdd(&ps[d], 1);
        sLoc[p] = (int)(e & 0x1FFFF);
    }
    __syncthreads();
    for (int i = t; i < nb; i += 256) ssrc[(size_t)b * BCAP + i] = sLoc[i];
}

// ---------------- weight prep: fragment-ordered bf16 ----------------
// mfma_f32_16x16x32_bf16 B-frag: lane holds B[k=(lane>>4)*8+j][n=lane&15].
__global__ __launch_bounds__(256)
void wprep_kernel(const float* __restrict__ W1, const float* __restrict__ W2,
                  short8* __restrict__ W1f, short8* __restrict__ W2f) {
    int b = blockIdx.x;
    if (b < 16) {
        int f = b * 256 + threadIdx.x;
        int k0 = f >> 9, nt = (f >> 6) & 7, ln = f & 63;
        int kbase = k0 * 32 + (ln >> 4) * 8;
        int n = nt * 16 + (ln & 15);
        short8 fr;
#pragma unroll
        for (int j = 0; j < 8; ++j) fr[j] = (short)bf16_rne(W1[(kbase + j) * F_MID + n]);
        W1f[f] = fr;
    } else {
        int f = (b - 16) * 256 + threadIdx.x;
        int k0 = f >> 8, nt = (f >> 6) & 3, ln = f & 63;
        int kbase = k0 * 32 + (ln >> 4) * 8;
        int n = nt * 16 + (ln & 15);
        short8 fr;
#pragma unroll
        for (int j = 0; j < 8; ++j) fr[j] = (short)bf16_rne(W2[(kbase + j) * F_OUT + n]);
        W2f[f] = fr;
    }
}

// ---------------- MFMA GEMM 1 (R13 128-row version) ----------------
// A: lane holds A[m=lane&15][k=(lane>>4)*8+j]; C/D: col=lane&15, row=(lane>>4)*4+reg.

// h1s[M,128](bf16) = dinv[m] * (x[M,256](fp32) @ W1bf16)
// 8 waves x 16 rows = 128-row tile. A staged per 64-col K-chunk into LDS as
// bf16 in A-frag order (coalesced global loads, convert during staging,
// XOR-swizzled slots). Double-buffered; 1 barrier/chunk.
__global__ __launch_bounds__(512, 2)
void gemm1_kernel(const float* __restrict__ A, const short8* __restrict__ Wf,
                  const float* __restrict__ dinv, ushort* __restrict__ C,
                  int M) {
    __shared__ short8 BsF[4096];          // 64 KB: W1 fragments
    __shared__ ushort Abuf[2][128 * 64];  // 2 x 16 KB: bf16 A chunks
    int tid = threadIdx.x;
    int lane = tid & 63, w = tid >> 6;    // w in 0..7
    int m0 = blockIdx.x * 128;

    int o0 = tid * 2;
    int srow = o0 >> 3;                   // both slots share the row
    int gr = m0 + srow; if (gr >= M) gr = m0;   // clamp (garbage rows unused)
    int cl0 = o0 & 7, cl1 = cl0 + 1;
    int cg0 = cl0 ^ (srow & 7), cg1 = cl1 ^ (srow & 7);
    const float* arow = &A[(size_t)gr * F_IN];

    float4 rv[2][2];
    rv[0][0] = ((const float4*)(arow + cg0 * 8))[0];
    rv[0][1] = ((const float4*)(arow + cg0 * 8))[1];
    rv[1][0] = ((const float4*)(arow + cg1 * 8))[0];
    rv[1][1] = ((const float4*)(arow + cg1 * 8))[1];

    for (int f = tid; f < 4096; f += 512) BsF[f] = Wf[f];

    {
        short8 pk;
        pk[0] = (short)bf16_rne(rv[0][0].x); pk[1] = (short)bf16_rne(rv[0][0].y);
        pk[2] = (short)bf16_rne(rv[0][0].z); pk[3] = (short)bf16_rne(rv[0][0].w);
        pk[4] = (short)bf16_rne(rv[0][1].x); pk[5] = (short)bf16_rne(rv[0][1].y);
        pk[6] = (short)bf16_rne(rv[0][1].z); pk[7] = (short)bf16_rne(rv[0][1].w);
        *(short8*)&Abuf[0][o0 * 8] = pk;
        pk[0] = (short)bf16_rne(rv[1][0].x); pk[1] = (short)bf16_rne(rv[1][0].y);
        pk[2] = (short)bf16_rne(rv[1][0].z); pk[3] = (short)bf16_rne(rv[1][0].w);
        pk[4] = (short)bf16_rne(rv[1][1].x); pk[5] = (short)bf16_rne(rv[1][1].y);
        pk[6] = (short)bf16_rne(rv[1][1].z); pk[7] = (short)bf16_rne(rv[1][1].w);
        *(short8*)&Abuf[0][(o0 + 1) * 8] = pk;
    }
    __syncthreads();

    f32x4 acc[8];
#pragma unroll
    for (int nt = 0; nt < 8; ++nt) acc[nt] = (f32x4){0.f, 0.f, 0.f, 0.f};

    int arow16 = w * 16 + (lane & 15);    // this lane's A-frag row in tile
    int asw = arow16 & 7;
    int abase = arow16 * 8;               // slot base for that row

#pragma unroll
    for (int kc = 0; kc < 4; ++kc) {
        int b = kc & 1;
        if (kc < 3) {
            const float* s0 = arow + (kc + 1) * 64 + cg0 * 8;
            const float* s1 = arow + (kc + 1) * 64 + cg1 * 8;
            rv[0][0] = ((const float4*)s0)[0];
            rv[0][1] = ((const float4*)s0)[1];
            rv[1][0] = ((const float4*)s1)[0];
            rv[1][1] = ((const float4*)s1)[1];
            asm volatile("" ::: "memory");
        }
#pragma unroll
        for (int kk = 0; kk < 2; ++kk) {
            int k0 = kc * 2 + kk;
            int c = kk * 4 + (lane >> 4);
            short8 af = *(const short8*)&Abuf[b][(abase + (c ^ asw)) * 8];
#pragma unroll
            for (int nt = 0; nt < 8; ++nt) {
                short8 bfr = BsF[(k0 * 8 + nt) * 64 + lane];
                acc[nt] = __builtin_amdgcn_mfma_f32_16x16x32_bf16(af, bfr, acc[nt], 0, 0, 0);
            }
        }
        if (kc < 3) {
            short8 pk;
            pk[0] = (short)bf16_rne(rv[0][0].x); pk[1] = (short)bf16_rne(rv[0][0].y);
            pk[2] = (short)bf16_rne(rv[0][0].z); pk[3] = (short)bf16_rne(rv[0][0].w);
            pk[4] = (short)bf16_rne(rv[0][1].x); pk[5] = (short)bf16_rne(rv[0][1].y);
            pk[6] = (short)bf16_rne(rv[0][1].z); pk[7] = (short)bf16_rne(rv[0][1].w);
            *(short8*)&Abuf[b ^ 1][o0 * 8] = pk;
            pk[0] = (short)bf16_rne(rv[1][0].x); pk[1] = (short)bf16_rne(rv[1][0].y);
            pk[2] = (short)bf16_rne(rv[1][0].z); pk[3] = (short)bf16_rne(rv[1][0].w);
            pk[4] = (short)bf16_rne(rv[1][1].x); pk[5] = (short)bf16_rne(rv[1][1].y);
            pk[6] = (short)bf16_rne(rv[1][1].z); pk[7] = (short)bf16_rne(rv[1][1].w);
            *(short8*)&Abuf[b ^ 1][(o0 + 1) * 8] = pk;
        }
        __syncthreads();
    }

#pragma unroll
    for (int i = 0; i < 4; ++i) {
        int r = blockIdx.x * 128 + w * 16 + (lane >> 4) * 4 + i;
        if (r < M) {
            float dv = dinv[r];
#pragma unroll
            for (int nt = 0; nt < 8; ++nt)
                C[(size_t)r * F_MID + nt * 16 + (lane & 15)] = bf16_rne(dv * acc[nt][i]);
        }
    }
}

// ---------------- fused aggregation-1 + gemm2 ----------------
// Block = 256 threads = 4 waves, 16 nodes. Phase 1: wave w serially
// aggregates nodes base+w*4+i (quarter q handles edges base+4j+q, x4
// unroll), applies dinv/b1/relu, stages the 128-col bf16 row into LDS
// (stride 136 shorts -> 2-way banks). Phase 2: wave w computes h2 col-tile
// nt=w for all 16 rows via 4 MFMAs: h2 = dinv * (rows @ W2).
__global__ __launch_bounds__(256)
void agg1f_kernel(const uint4* __restrict__ h, const int* __restrict__ rs,
                  const int* __restrict__ cnt, const int* __restrict__ ssrc,
                  const float* __restrict__ dinv, const float* __restrict__ bias,
                  const short8* __restrict__ W2f, ushort* __restrict__ h2, int n) {
    __shared__ __align__(16) ushort rowsL[16][136];   // 16 rows x 128 bf16 + pad
    int w = threadIdx.x >> 6, lane = threadIdx.x & 63;
    int q = lane >> 4, c16 = lane & 15;
    int nbase = blockIdx.x * 16;
    const float4* b4 = (const float4*)bias;
    float4 b0 = b4[c16 * 2], b1v = b4[c16 * 2 + 1];

#pragma unroll
    for (int i = 0; i < 4; ++i) {
        int node = nbase + w * 4 + i;
        bool nOk = (node < n);
        int start = nOk ? rs[node] : 0;
        int c = nOk ? cnt[node] : 0;
        float dn = nOk ? dinv[node] : 0.f;
        float a[8];
#pragma unroll
        for (int k = 0; k < 8; ++k) a[k] = 0.f;

        for (int base = 0; base < c; base += 16) {
            bool p[4];
            int s[4];
            uint4 r[4];
#pragma unroll
            for (int j = 0; j < 4; ++j) {
                int e = base + j * 4 + q;
                p[j] = e < c;
                if (p[j]) s[j] = ssrc[start + e];
            }
#pragma unroll
            for (int j = 0; j < 4; ++j)
                if (p[j]) r[j] = h[(size_t)s[j] * 16 + c16];
#pragma unroll
            for (int j = 0; j < 4; ++j) {
                if (p[j]) {
                    a[0] += lo16(r[j].x); a[1] += hi16(r[j].x);
                    a[2] += lo16(r[j].y); a[3] += hi16(r[j].y);
                    a[4] += lo16(r[j].z); a[5] += hi16(r[j].z);
                    a[6] += lo16(r[j].w); a[7] += hi16(r[j].w);
                }
            }
        }
#pragma unroll
        for (int k = 0; k < 8; ++k) {
            a[k] += __shfl_xor(a[k], 16);
            a[k] += __shfl_xor(a[k], 32);
        }
        if (q == 0) {
            short8 pk;
            if (nOk) {
                uint4 sr = h[(size_t)node * 16 + c16];
                float o0 = fmaxf(fmaf(dn, a[0] + lo16(sr.x), b0.x), 0.f);
                float o1 = fmaxf(fmaf(dn, a[1] + hi16(sr.x), b0.y), 0.f);
                float o2 = fmaxf(fmaf(dn, a[2] + lo16(sr.y), b0.z), 0.f);
                float o3 = fmaxf(fmaf(dn, a[3] + hi16(sr.y), b0.w), 0.f);
                float o4 = fmaxf(fmaf(dn, a[4] + lo16(sr.z), b1v.x), 0.f);
                float o5 = fmaxf(fmaf(dn, a[5] + hi16(sr.z), b1v.y), 0.f);
                float o6 = fmaxf(fmaf(dn, a[6] + lo16(sr.w), b1v.z), 0.f);
                float o7 = fmaxf(fmaf(dn, a[7] + hi16(sr.w), b1v.w), 0.f);
                pk[0] = (short)bf16_rne(o0); pk[1] = (short)bf16_rne(o1);
                pk[2] = (short)bf16_rne(o2); pk[3] = (short)bf16_rne(o3);
                pk[4] = (short)bf16_rne(o4); pk[5] = (short)bf16_rne(o5);
                pk[6] = (short)bf16_rne(o6); pk[7] = (short)bf16_rne(o7);
            } else {
                pk = (short8){0, 0, 0, 0, 0, 0, 0, 0};
            }
            *(short8*)&rowsL[w * 4 + i][c16 * 8] = pk;
        }
    }
    __syncthreads();

    // phase 2: wave w -> col-tile nt=w. A: lane reads LDS row (lane&15),
    // k-slice k0*32+(lane>>4)*8; B: W2f[(k0*4+w)*64+lane] (L2-hot, 16 KB).
    f32x4 acc = (f32x4){0.f, 0.f, 0.f, 0.f};
    int ar = lane & 15;
#pragma unroll
    for (int k0 = 0; k0 < 4; ++k0) {
        short8 af = *(const short8*)&rowsL[ar][k0 * 32 + (lane >> 4) * 8];
        short8 bfr = W2f[(k0 * 4 + w) * 64 + lane];
        acc = __builtin_amdgcn_mfma_f32_16x16x32_bf16(af, bfr, acc, 0, 0, 0);
    }
#pragma unroll
    for (int i = 0; i < 4; ++i) {
        int r = (lane >> 4) * 4 + i;
        int node = nbase + r;
        if (node < n) {
            float dv = dinv[node];
            h2[(size_t)node * F_OUT + w * 16 + (lane & 15)] = bf16_rne(dv * acc[i]);
        }
    }
}

// agg2: 64-col bf16 rows (128 B), 16 lanes x uint2; x4-unrolled gather;
// fused bias + log_softmax.
__global__ __launch_bounds__(256)
void agg2_kernel(const uint2* __restrict__ h, const int* __restrict__ rs,
                 const int* __restrict__ cnt, const int* __restrict__ ssrc,
                 const float* __restrict__ dinv, const float* __restrict__ bias,
                 float4* __restrict__ out4, int n) {
    int w = threadIdx.x >> 6, lane = threadIdx.x & 63;
    int node = blockIdx.x * 4 + w;
    if (node >= n) return;
    int q = lane >> 4, c16 = lane & 15;
    int start = rs[node], c = cnt[node];
    float dn = dinv[node];
    float a[4];
#pragma unroll
    for (int i = 0; i < 4; ++i) a[i] = 0.f;

    for (int base = 0; base < c; base += 16) {
        bool p[4];
        int s[4];
        uint2 r[4];
#pragma unroll
        for (int j = 0; j < 4; ++j) {
            int e = base + j * 4 + q;
            p[j] = e < c;
            if (p[j]) s[j] = ssrc[start + e];
        }
#pragma unroll
        for (int j = 0; j < 4; ++j)
            if (p[j]) r[j] = h[(size_t)s[j] * 16 + c16];
#pragma unroll
        for (int j = 0; j < 4; ++j) {
            if (p[j]) {
                a[0] += lo16(r[j].x); a[1] += hi16(r[j].x);
                a[2] += lo16(r[j].y); a[3] += hi16(r[j].y);
            }
        }
    }
#pragma unroll
    for (int i = 0; i < 4; ++i) {
        a[i] += __shfl_xor(a[i], 16);
        a[i] += __shfl_xor(a[i], 32);
    }
    uint2 sr = h[(size_t)node * 16 + c16];
    float4 bv = ((const float4*)bias)[c16];
    float v0 = fmaf(dn, a[0] + lo16(sr.x), bv.x);
    float v1 = fmaf(dn, a[1] + hi16(sr.x), bv.y);
    float v2 = fmaf(dn, a[2] + lo16(sr.y), bv.z);
    float v3 = fmaf(dn, a[3] + hi16(sr.y), bv.w);
    float m = fmaxf(fmaxf(v0, v1), fmaxf(v2, v3));
#pragma unroll
    for (int off = 1; off < 16; off <<= 1) m = fmaxf(m, __shfl_xor(m, off));
    float ssum = expf(v0 - m) + expf(v1 - m) + expf(v2 - m) + expf(v3 - m);
#pragma unroll
    for (int off = 1; off < 16; off <<= 1) ssum += __shfl_xor(ssum, off);
    float lg = m + logf(ssum);
    if (q == 0) out4[(size_t)node * 16 + c16] = make_float4(v0 - lg, v1 - lg, v2 - lg, v3 - lg);
}

// ---------------- launch ----------------

extern "C" void kernel_launch(void* const* d_in, const int* in_sizes, int n_in,
                              void* d_out, int out_size, void* d_ws, size_t ws_size,
                              hipStream_t stream) {
    const float* x  = (const float*)d_in[0];
    const int*   ei = (const int*)d_in[1];
    const float* W1 = (const float*)d_in[2];
    const float* b1 = (const float*)d_in[3];
    const float* W2 = (const float*)d_in[4];
    const float* b2 = (const float*)d_in[5];
    float* out = (float*)d_out;

    const int N = N_NODES;
    const int E = in_sizes[1] / 2;
    const int* src = ei;
    const int* dst = ei + E;

    char* ws = (char*)d_ws;
    size_t off = 0;
    auto alloc = [&](size_t bytes) {
        char* p = ws + off;
        off = (off + bytes + 255) & ~(size_t)255;
        return p;
    };
    int*    bcur   = (int*)alloc(NBUCKETS * 4);
    int*    rs     = (int*)alloc(N * 4);
    int*    cnt    = (int*)alloc(N * 4);
    float*  dinv   = (float*)alloc(N * 4);
    short8* W1f    = (short8*)alloc(4096 * 16);
    short8* W2f    = (short8*)alloc(1024 * 16);
    uint*   ebuf   = (uint*)alloc((size_t)NBUCKETS * BCAP * 4);   // 9.6 MB
    int*    ssrc   = (int*)alloc((size_t)NBUCKETS * BCAP * 4);    // 9.6 MB
    uint*   h1     = (uint*)alloc((size_t)N * 64 * 4);            // 128 bf16/row
    ushort* h2     = (ushort*)alloc((size_t)N * 64 * 2);          // 64 bf16/row

    const int nScatBlocks = (E + EPB - 1) / EPB;         // 391
    const int nAgg1Blocks = (N + 15) / 16;               // 6250
    const int nAgg2Blocks = (N + 3) / 4;
    const int nTiles      = (N + 127) / 128;             // 782

    hipMemsetAsync(bcur, 0, NBUCKETS * 4, stream);
    wprep_kernel<<<20, 256, 0, stream>>>(W1, W2, W1f, W2f);

    bucket_scatter_kernel<<<nScatBlocks, 256, 0, stream>>>(src, dst, bcur, ebuf, E);
    bucket_sort_kernel<<<NBUCKETS, 256, 0, stream>>>(ebuf, bcur, ssrc, rs, cnt, dinv, N);

    gemm1_kernel<<<nTiles, 512, 0, stream>>>(x, W1f, dinv, (ushort*)h1, N);
    agg1f_kernel<<<nAgg1Blocks, 256, 0, stream>>>((const uint4*)h1, rs, cnt, ssrc, dinv, b1,
                                                  W2f, h2, N);
    agg2_kernel<<<nAgg2Blocks, 256, 0, stream>>>((const uint2*)h2, rs, cnt, ssrc, dinv, b2,
                                                 (float4*)out, N);
}

// Round 11
// 352.949 us; speedup vs baseline: 1.0701x; 1.0179x over previous
//
#include <hip/hip_runtime.h>
#include <hip/hip_bf16.h>

// GCN 2-layer: out = log_softmax(GCN2(relu(GCN1(x))))
// Round 18: (1) gemm1 v3 -- W LDS table REMOVED; W fragments read straight
// from global per MFMA (128-KB W1f is L2-hot; repeated reads are L2 hits,
// the per-block 64-KB restage was ~50 MB of L2-fill = ~20us of gemm1's
// ~60). LDS drops 96->32 KB (A dbuf only) -> 2 blocks/CU under (512,4),
// giving R16's cross-block overlap without R16's W-amortization loss.
// Same proven pattern as agg1f phase-2's direct W2f reads.
// (2) agg2 v2 -- 2 nodes per wave, gathers interleaved: 32 edges x 128 B
// = 4 KB in flight/wave (was 2 KB), matching agg1f's MLP; wave count
// halved. (3) FETCH_SIZE insight: TCC counters = per-XCD L2 fill, so
// agg1f's 189 MB = footprint x 8 XCDs once-per-XCD fill = structural
// floor -> agg1f frozen.
// scatter/sort v2 (R17), agg1f, wprep frozen.

#define N_NODES 100000
#define F_IN 256
#define F_MID 128
#define F_OUT 64

#define BSHIFT 8                      // 256 nodes per bucket
#define BNODES 256
#define NBUCKETS ((N_NODES + BNODES - 1) / BNODES)   // 391
#define BCAP 6144                     // mean 4096, sigma ~64 -> +32 sigma
#define EPB 4096                      // edges per scatter block

typedef __attribute__((ext_vector_type(8))) short short8;
typedef __attribute__((ext_vector_type(4))) float f32x4;

__device__ inline ushort bf16_rne(float f) {
    uint u = __float_as_uint(f);
    u += 0x7FFF + ((u >> 16) & 1);
    return (ushort)(u >> 16);
}
__device__ inline float lo16(uint r) { return __uint_as_float(r << 16); }
__device__ inline float hi16(uint r) { return __uint_as_float(r & 0xffff0000u); }
__device__ inline uint pack_bf2(float a, float b) {
    return (uint)bf16_rne(a) | ((uint)bf16_rne(b) << 16);
}

// ---------------- two-level bucket sort ----------------

// S1 v2: block-local counting sort by bucket, chunked coalesced copy-out.
// packed = (dst&255)<<17 | src  (25 bits)
__global__ __launch_bounds__(256)
void bucket_scatter_kernel(const int* __restrict__ src, const int* __restrict__ dst,
                           int* __restrict__ bcur, uint* __restrict__ ebuf, int E) {
    __shared__ int hist[512], ps[512], cur[512];
    __shared__ int base[NBUCKETS];
    __shared__ uint   eLoc[EPB];      // 16 KB packed edges, bucket-grouped
    __shared__ ushort bLoc[EPB];      // 8 KB bucket id per local slot
    int t = threadIdx.x;
    int e0 = blockIdx.x * EPB;
    int e1 = e0 + EPB; if (e1 > E) e1 = E;
    int ne = e1 - e0;

    for (int i = t; i < 512; i += 256) hist[i] = 0;
    __syncthreads();
    for (int i = t; i < ne; i += 256) atomicAdd(&hist[dst[e0 + i] >> BSHIFT], 1);
    __syncthreads();
    // inclusive Hillis-Steele over 512 bins, 2 elems/thread
    ps[t] = hist[t]; ps[t + 256] = hist[t + 256];
    __syncthreads();
#pragma unroll
    for (int off = 1; off < 512; off <<= 1) {
        int i0 = t, i1 = t + 256;
        int v0 = (i0 >= off) ? ps[i0 - off] : 0;
        int v1 = (i1 >= off) ? ps[i1 - off] : 0;
        __syncthreads();
        ps[i0] += v0; ps[i1] += v1;
        __syncthreads();
    }
    // ps -> exclusive; cur = running cursor
    {
        int ex0 = ps[t] - hist[t];
        int ex1 = ps[t + 256] - hist[t + 256];
        __syncthreads();
        ps[t] = ex0; ps[t + 256] = ex1;
        cur[t] = ex0; cur[t + 256] = ex1;
    }
    __syncthreads();
    // local scatter into LDS (bucket-grouped)
    for (int i = t; i < ne; i += 256) {
        int d = dst[e0 + i], s = src[e0 + i];
        int b = d >> BSHIFT;
        int p = atomicAdd(&cur[b], 1);
        eLoc[p] = ((uint)(d & (BNODES - 1)) << 17) | (uint)s;
        bLoc[p] = (ushort)b;
    }
    __syncthreads();
    // reserve global ranges (one atomic per non-empty bucket)
    for (int b = t; b < NBUCKETS; b += 256) {
        int h = hist[b];
        base[b] = h ? atomicAdd(&bcur[b], h) : 0;
    }
    __syncthreads();
    // chunked copy-out: consecutive local slots of a bucket -> consecutive
    // global addresses (coalesced ~40-B bursts)
    for (int i = t; i < ne; i += 256) {
        int b = bLoc[i];
        int d = base[b] + (i - ps[b]);
        if (d < BCAP) ebuf[(size_t)b * BCAP + d] = eLoc[i];
    }
}

// S2 v2: per-bucket counting sort; sorted list built in LDS then streamed
// out coalesced. Emits ssrc + rs + cnt + dinv.
__global__ __launch_bounds__(256)
void bucket_sort_kernel(const uint* __restrict__ ebuf, const int* __restrict__ bcur,
                        int* __restrict__ ssrc, int* __restrict__ rs, int* __restrict__ cnt,
                        float* __restrict__ dinv, int n) {
    __shared__ uint eL[BCAP];          // 24 KB
    __shared__ int  sLoc[BCAP];        // 24 KB sorted srcs
    __shared__ int hist[BNODES], ps[BNODES];
    int b = blockIdx.x, t = threadIdx.x;
    int nb = bcur[b];
    if (nb > BCAP) nb = BCAP;
    for (int i = t; i < nb; i += 256) eL[i] = ebuf[(size_t)b * BCAP + i];
    hist[t] = 0;
    __syncthreads();
    for (int i = t; i < nb; i += 256) atomicAdd(&hist[eL[i] >> 17], 1);
    __syncthreads();
    ps[t] = hist[t];
    __syncthreads();
#pragma unroll
    for (int off = 1; off < BNODES; off <<= 1) {
        int v = (t >= off) ? ps[t - off] : 0;
        __syncthreads();
        ps[t] += v;
        __syncthreads();
    }
    int excl = ps[t] - hist[t];
    int node = b * BNODES + t;
    if (node < n) {
        rs[node] = b * BCAP + excl;
        cnt[node] = hist[t];
        dinv[node] = 1.0f / sqrtf((float)hist[t] + 1.0f);
    }
    __syncthreads();
    ps[t] = excl;                      // reuse as running cursor
    __syncthreads();
    for (int i = t; i < nb; i += 256) {
        uint e = eL[i];
        int d = e >> 17;
        int p = atomicAdd(&ps[d], 1);
        sLoc[p] = (int)(e & 0x1FFFF);
    }
    __syncthreads();
    for (int i = t; i < nb; i += 256) ssrc[(size_t)b * BCAP + i] = sLoc[i];
}

// ---------------- weight prep: fragment-ordered bf16 ----------------
// mfma_f32_16x16x32_bf16 B-frag: lane holds B[k=(lane>>4)*8+j][n=lane&15].
__global__ __launch_bounds__(256)
void wprep_kernel(const float* __restrict__ W1, const float* __restrict__ W2,
                  short8* __restrict__ W1f, short8* __restrict__ W2f) {
    int b = blockIdx.x;
    if (b < 16) {
        int f = b * 256 + threadIdx.x;
        int k0 = f >> 9, nt = (f >> 6) & 7, ln = f & 63;
        int kbase = k0 * 32 + (ln >> 4) * 8;
        int n = nt * 16 + (ln & 15);
        short8 fr;
#pragma unroll
        for (int j = 0; j < 8; ++j) fr[j] = (short)bf16_rne(W1[(kbase + j) * F_MID + n]);
        W1f[f] = fr;
    } else {
        int f = (b - 16) * 256 + threadIdx.x;
        int k0 = f >> 8, nt = (f >> 6) & 3, ln = f & 63;
        int kbase = k0 * 32 + (ln >> 4) * 8;
        int n = nt * 16 + (ln & 15);
        short8 fr;
#pragma unroll
        for (int j = 0; j < 8; ++j) fr[j] = (short)bf16_rne(W2[(kbase + j) * F_OUT + n]);
        W2f[f] = fr;
    }
}

// ---------------- MFMA GEMM 1 (v3: direct-from-L2 W reads) ----------------
// A: lane holds A[m=lane&15][k=(lane>>4)*8+j]; C/D: col=lane&15, row=(lane>>4)*4+reg.

// h1s[M,128](bf16) = dinv[m] * (x[M,256](fp32) @ W1bf16)
// 8 waves x 16 rows = 128-row tile. A staged per 64-col K-chunk into LDS
// (coalesced, convert during staging, XOR-swizzled, double-buffered).
// W fragments read directly from global (L2-hot 128 KB) -- no LDS table,
// no per-block restage fill. LDS 32 KB -> 2 blocks/CU at <=128 regs.
__global__ __launch_bounds__(512, 4)
void gemm1_kernel(const float* __restrict__ A, const short8* __restrict__ Wf,
                  const float* __restrict__ dinv, ushort* __restrict__ C,
                  int M) {
    __shared__ ushort Abuf[2][128 * 64];  // 2 x 16 KB: bf16 A chunks
    int tid = threadIdx.x;
    int lane = tid & 63, w = tid >> 6;    // w in 0..7
    int m0 = blockIdx.x * 128;

    int o0 = tid * 2;
    int srow = o0 >> 3;                   // both slots share the row
    int gr = m0 + srow; if (gr >= M) gr = m0;   // clamp (garbage rows unused)
    int cl0 = o0 & 7, cl1 = cl0 + 1;
    int cg0 = cl0 ^ (srow & 7), cg1 = cl1 ^ (srow & 7);
    const float* arow = &A[(size_t)gr * F_IN];

    float4 rv[2][2];
    rv[0][0] = ((const float4*)(arow + cg0 * 8))[0];
    rv[0][1] = ((const float4*)(arow + cg0 * 8))[1];
    rv[1][0] = ((const float4*)(arow + cg1 * 8))[0];
    rv[1][1] = ((const float4*)(arow + cg1 * 8))[1];

    {
        short8 pk;
        pk[0] = (short)bf16_rne(rv[0][0].x); pk[1] = (short)bf16_rne(rv[0][0].y);
        pk[2] = (short)bf16_rne(rv[0][0].z); pk[3] = (short)bf16_rne(rv[0][0].w);
        pk[4] = (short)bf16_rne(rv[0][1].x); pk[5] = (short)bf16_rne(rv[0][1].y);
        pk[6] = (short)bf16_rne(rv[0][1].z); pk[7] = (short)bf16_rne(rv[0][1].w);
        *(short8*)&Abuf[0][o0 * 8] = pk;
        pk[0] = (short)bf16_rne(rv[1][0].x); pk[1] = (short)bf16_rne(rv[1][0].y);
        pk[2] = (short)bf16_rne(rv[1][0].z); pk[3] = (short)bf16_rne(rv[1][0].w);
        pk[4] = (short)bf16_rne(rv[1][1].x); pk[5] = (short)bf16_rne(rv[1][1].y);
        pk[6] = (short)bf16_rne(rv[1][1].z); pk[7] = (short)bf16_rne(rv[1][1].w);
        *(short8*)&Abuf[0][(o0 + 1) * 8] = pk;
    }
    __syncthreads();

    f32x4 acc[8];
#pragma unroll
    for (int nt = 0; nt < 8; ++nt) acc[nt] = (f32x4){0.f, 0.f, 0.f, 0.f};

    int arow16 = w * 16 + (lane & 15);    // this lane's A-frag row in tile
    int asw = arow16 & 7;
    int abase = arow16 * 8;               // slot base for that row

#pragma unroll
    for (int kc = 0; kc < 4; ++kc) {
        int b = kc & 1;
        if (kc < 3) {
            const float* s0 = arow + (kc + 1) * 64 + cg0 * 8;
            const float* s1 = arow + (kc + 1) * 64 + cg1 * 8;
            rv[0][0] = ((const float4*)s0)[0];
            rv[0][1] = ((const float4*)s0)[1];
            rv[1][0] = ((const float4*)s1)[0];
            rv[1][1] = ((const float4*)s1)[1];
            asm volatile("" ::: "memory");
        }
#pragma unroll
        for (int kk = 0; kk < 2; ++kk) {
            int k0 = kc * 2 + kk;
            int c = kk * 4 + (lane >> 4);
            short8 af = *(const short8*)&Abuf[b][(abase + (c ^ asw)) * 8];
#pragma unroll
            for (int nt = 0; nt < 8; ++nt) {
                short8 bfr = Wf[(k0 * 8 + nt) * 64 + lane];   // L2-hit read
                acc[nt] = __builtin_amdgcn_mfma_f32_16x16x32_bf16(af, bfr, acc[nt], 0, 0, 0);
            }
        }
        if (kc < 3) {
            short8 pk;
            pk[0] = (short)bf16_rne(rv[0][0].x); pk[1] = (short)bf16_rne(rv[0][0].y);
            pk[2] = (short)bf16_rne(rv[0][0].z); pk[3] = (short)bf16_rne(rv[0][0].w);
            pk[4] = (short)bf16_rne(rv[0][1].x); pk[5] = (short)bf16_rne(rv[0][1].y);
            pk[6] = (short)bf16_rne(rv[0][1].z); pk[7] = (short)bf16_rne(rv[0][1].w);
            *(short8*)&Abuf[b ^ 1][o0 * 8] = pk;
            pk[0] = (short)bf16_rne(rv[1][0].x); pk[1] = (short)bf16_rne(rv[1][0].y);
            pk[2] = (short)bf16_rne(rv[1][0].z); pk[3] = (short)bf16_rne(rv[1][0].w);
            pk[4] = (short)bf16_rne(rv[1][1].x); pk[5] = (short)bf16_rne(rv[1][1].y);
            pk[6] = (short)bf16_rne(rv[1][1].z); pk[7] = (short)bf16_rne(rv[1][1].w);
            *(short8*)&Abuf[b ^ 1][(o0 + 1) * 8] = pk;
        }
        __syncthreads();
    }

#pragma unroll
    for (int i = 0; i < 4; ++i) {
        int r = blockIdx.x * 128 + w * 16 + (lane >> 4) * 4 + i;
        if (r < M) {
            float dv = dinv[r];
#pragma unroll
            for (int nt = 0; nt < 8; ++nt)
                C[(size_t)r * F_MID + nt * 16 + (lane & 15)] = bf16_rne(dv * acc[nt][i]);
        }
    }
}

// ---------------- fused aggregation-1 + gemm2 ----------------
// Block = 256 threads = 4 waves, 16 nodes. Phase 1: wave w serially
// aggregates nodes base+w*4+i (quarter q handles edges base+4j+q, x4
// unroll), applies dinv/b1/relu, stages the 128-col bf16 row into LDS
// (stride 136 shorts -> 2-way banks). Phase 2: wave w computes h2 col-tile
// nt=w for all 16 rows via 4 MFMAs: h2 = dinv * (rows @ W2).
__global__ __launch_bounds__(256)
void agg1f_kernel(const uint4* __restrict__ h, const int* __restrict__ rs,
                  const int* __restrict__ cnt, const int* __restrict__ ssrc,
                  const float* __restrict__ dinv, const float* __restrict__ bias,
                  const short8* __restrict__ W2f, ushort* __restrict__ h2, int n) {
    __shared__ __align__(16) ushort rowsL[16][136];   // 16 rows x 128 bf16 + pad
    int w = threadIdx.x >> 6, lane = threadIdx.x & 63;
    int q = lane >> 4, c16 = lane & 15;
    int nbase = blockIdx.x * 16;
    const float4* b4 = (const float4*)bias;
    float4 b0 = b4[c16 * 2], b1v = b4[c16 * 2 + 1];

#pragma unroll
    for (int i = 0; i < 4; ++i) {
        int node = nbase + w * 4 + i;
        bool nOk = (node < n);
        int start = nOk ? rs[node] : 0;
        int c = nOk ? cnt[node] : 0;
        float dn = nOk ? dinv[node] : 0.f;
        float a[8];
#pragma unroll
        for (int k = 0; k < 8; ++k) a[k] = 0.f;

        for (int base = 0; base < c; base += 16) {
            bool p[4];
            int s[4];
            uint4 r[4];
#pragma unroll
            for (int j = 0; j < 4; ++j) {
                int e = base + j * 4 + q;
                p[j] = e < c;
                if (p[j]) s[j] = ssrc[start + e];
            }
#pragma unroll
            for (int j = 0; j < 4; ++j)
                if (p[j]) r[j] = h[(size_t)s[j] * 16 + c16];
#pragma unroll
            for (int j = 0; j < 4; ++j) {
                if (p[j]) {
                    a[0] += lo16(r[j].x); a[1] += hi16(r[j].x);
                    a[2] += lo16(r[j].y); a[3] += hi16(r[j].y);
                    a[4] += lo16(r[j].z); a[5] += hi16(r[j].z);
                    a[6] += lo16(r[j].w); a[7] += hi16(r[j].w);
                }
            }
        }
#pragma unroll
        for (int k = 0; k < 8; ++k) {
            a[k] += __shfl_xor(a[k], 16);
            a[k] += __shfl_xor(a[k], 32);
        }
        if (q == 0) {
            short8 pk;
            if (nOk) {
                uint4 sr = h[(size_t)node * 16 + c16];
                float o0 = fmaxf(fmaf(dn, a[0] + lo16(sr.x), b0.x), 0.f);
                float o1 = fmaxf(fmaf(dn, a[1] + hi16(sr.x), b0.y), 0.f);
                float o2 = fmaxf(fmaf(dn, a[2] + lo16(sr.y), b0.z), 0.f);
                float o3 = fmaxf(fmaf(dn, a[3] + hi16(sr.y), b0.w), 0.f);
                float o4 = fmaxf(fmaf(dn, a[4] + lo16(sr.z), b1v.x), 0.f);
                float o5 = fmaxf(fmaf(dn, a[5] + hi16(sr.z), b1v.y), 0.f);
                float o6 = fmaxf(fmaf(dn, a[6] + lo16(sr.w), b1v.z), 0.f);
                float o7 = fmaxf(fmaf(dn, a[7] + hi16(sr.w), b1v.w), 0.f);
                pk[0] = (short)bf16_rne(o0); pk[1] = (short)bf16_rne(o1);
                pk[2] = (short)bf16_rne(o2); pk[3] = (short)bf16_rne(o3);
                pk[4] = (short)bf16_rne(o4); pk[5] = (short)bf16_rne(o5);
                pk[6] = (short)bf16_rne(o6); pk[7] = (short)bf16_rne(o7);
            } else {
                pk = (short8){0, 0, 0, 0, 0, 0, 0, 0};
            }
            *(short8*)&rowsL[w * 4 + i][c16 * 8] = pk;
        }
    }
    __syncthreads();

    // phase 2: wave w -> col-tile nt=w. A: lane reads LDS row (lane&15),
    // k-slice k0*32+(lane>>4)*8; B: W2f[(k0*4+w)*64+lane] (L2-hot, 16 KB).
    f32x4 acc = (f32x4){0.f, 0.f, 0.f, 0.f};
    int ar = lane & 15;
#pragma unroll
    for (int k0 = 0; k0 < 4; ++k0) {
        short8 af = *(const short8*)&rowsL[ar][k0 * 32 + (lane >> 4) * 8];
        short8 bfr = W2f[(k0 * 4 + w) * 64 + lane];
        acc = __builtin_amdgcn_mfma_f32_16x16x32_bf16(af, bfr, acc, 0, 0, 0);
    }
#pragma unroll
    for (int i = 0; i < 4; ++i) {
        int r = (lane >> 4) * 4 + i;
        int node = nbase + r;
        if (node < n) {
            float dv = dinv[node];
            h2[(size_t)node * F_OUT + w * 16 + (lane & 15)] = bf16_rne(dv * acc[i]);
        }
    }
}

// agg2 v2: 64-col bf16 rows (128 B), 16 lanes x uint2; TWO nodes per wave
// with interleaved x4-unrolled gathers (32 edges / 4 KB in flight per
// wave); fused bias + log_softmax.
__global__ __launch_bounds__(256)
void agg2_kernel(const uint2* __restrict__ h, const int* __restrict__ rs,
                 const int* __restrict__ cnt, const int* __restrict__ ssrc,
                 const float* __restrict__ dinv, const float* __restrict__ bias,
                 float4* __restrict__ out4, int n) {
    int w = threadIdx.x >> 6, lane = threadIdx.x & 63;
    int q = lane >> 4, c16 = lane & 15;
    int nodeA = blockIdx.x * 8 + w * 2;
    int nodeB = nodeA + 1;
    bool okA = (nodeA < n), okB = (nodeB < n);
    if (!okA) return;
    int startA = rs[nodeA], cA = cnt[nodeA];
    int startB = okB ? rs[nodeB] : 0, cB = okB ? cnt[nodeB] : 0;
    float dnA = dinv[nodeA];
    float dnB = okB ? dinv[nodeB] : 0.f;
    float aA[4], aB[4];
#pragma unroll
    for (int i = 0; i < 4; ++i) { aA[i] = 0.f; aB[i] = 0.f; }

    int cm = cA > cB ? cA : cB;
    for (int base = 0; base < cm; base += 16) {
        bool pA[4], pB[4];
        int sA[4], sB[4];
        uint2 rA[4], rB[4];
#pragma unroll
        for (int j = 0; j < 4; ++j) {
            int e = base + j * 4 + q;
            pA[j] = e < cA;
            pB[j] = e < cB;
            if (pA[j]) sA[j] = ssrc[startA + e];
            if (pB[j]) sB[j] = ssrc[startB + e];
        }
#pragma unroll
        for (int j = 0; j < 4; ++j) {
            if (pA[j]) rA[j] = h[(size_t)sA[j] * 16 + c16];
            if (pB[j]) rB[j] = h[(size_t)sB[j] * 16 + c16];
        }
#pragma unroll
        for (int j = 0; j < 4; ++j) {
            if (pA[j]) {
                aA[0] += lo16(rA[j].x); aA[1] += hi16(rA[j].x);
                aA[2] += lo16(rA[j].y); aA[3] += hi16(rA[j].y);
            }
            if (pB[j]) {
                aB[0] += lo16(rB[j].x); aB[1] += hi16(rB[j].x);
                aB[2] += lo16(rB[j].y); aB[3] += hi16(rB[j].y);
            }
        }
    }
#pragma unroll
    for (int i = 0; i < 4; ++i) {
        aA[i] += __shfl_xor(aA[i], 16);
        aA[i] += __shfl_xor(aA[i], 32);
        aB[i] += __shfl_xor(aB[i], 16);
        aB[i] += __shfl_xor(aB[i], 32);
    }
    float4 bv = ((const float4*)bias)[c16];
    // node A
    {
        uint2 sr = h[(size_t)nodeA * 16 + c16];
        float v0 = fmaf(dnA, aA[0] + lo16(sr.x), bv.x);
        float v1 = fmaf(dnA, aA[1] + hi16(sr.x), bv.y);
        float v2 = fmaf(dnA, aA[2] + lo16(sr.y), bv.z);
        float v3 = fmaf(dnA, aA[3] + hi16(sr.y), bv.w);
        float m = fmaxf(fmaxf(v0, v1), fmaxf(v2, v3));
#pragma unroll
        for (int off = 1; off < 16; off <<= 1) m = fmaxf(m, __shfl_xor(m, off));
        float ssum = expf(v0 - m) + expf(v1 - m) + expf(v2 - m) + expf(v3 - m);
#pragma unroll
        for (int off = 1; off < 16; off <<= 1) ssum += __shfl_xor(ssum, off);
        float lg = m + logf(ssum);
        if (q == 0) out4[(size_t)nodeA * 16 + c16] = make_float4(v0 - lg, v1 - lg, v2 - lg, v3 - lg);
    }
    // node B
    if (okB) {
        uint2 sr = h[(size_t)nodeB * 16 + c16];
        float v0 = fmaf(dnB, aB[0] + lo16(sr.x), bv.x);
        float v1 = fmaf(dnB, aB[1] + hi16(sr.x), bv.y);
        float v2 = fmaf(dnB, aB[2] + lo16(sr.y), bv.z);
        float v3 = fmaf(dnB, aB[3] + hi16(sr.y), bv.w);
        float m = fmaxf(fmaxf(v0, v1), fmaxf(v2, v3));
#pragma unroll
        for (int off = 1; off < 16; off <<= 1) m = fmaxf(m, __shfl_xor(m, off));
        float ssum = expf(v0 - m) + expf(v1 - m) + expf(v2 - m) + expf(v3 - m);
#pragma unroll
        for (int off = 1; off < 16; off <<= 1) ssum += __shfl_xor(ssum, off);
        float lg = m + logf(ssum);
        if (q == 0) out4[(size_t)nodeB * 16 + c16] = make_float4(v0 - lg, v1 - lg, v2 - lg, v3 - lg);
    }
}

// ---------------- launch ----------------

extern "C" void kernel_launch(void* const* d_in, const int* in_sizes, int n_in,
                              void* d_out, int out_size, void* d_ws, size_t ws_size,
                              hipStream_t stream) {
    const float* x  = (const float*)d_in[0];
    const int*   ei = (const int*)d_in[1];
    const float* W1 = (const float*)d_in[2];
    const float* b1 = (const float*)d_in[3];
    const float* W2 = (const float*)d_in[4];
    const float* b2 = (const float*)d_in[5];
    float* out = (float*)d_out;

    const int N = N_NODES;
    const int E = in_sizes[1] / 2;
    const int* src = ei;
    const int* dst = ei + E;

    char* ws = (char*)d_ws;
    size_t off = 0;
    auto alloc = [&](size_t bytes) {
        char* p = ws + off;
        off = (off + bytes + 255) & ~(size_t)255;
        return p;
    };
    int*    bcur   = (int*)alloc(NBUCKETS * 4);
    int*    rs     = (int*)alloc(N * 4);
    int*    cnt    = (int*)alloc(N * 4);
    float*  dinv   = (float*)alloc(N * 4);
    short8* W1f    = (short8*)alloc(4096 * 16);
    short8* W2f    = (short8*)alloc(1024 * 16);
    uint*   ebuf   = (uint*)alloc((size_t)NBUCKETS * BCAP * 4);   // 9.6 MB
    int*    ssrc   = (int*)alloc((size_t)NBUCKETS * BCAP * 4);    // 9.6 MB
    uint*   h1     = (uint*)alloc((size_t)N * 64 * 4);            // 128 bf16/row
    ushort* h2     = (ushort*)alloc((size_t)N * 64 * 2);          // 64 bf16/row

    const int nScatBlocks = (E + EPB - 1) / EPB;         // 391
    const int nAgg1Blocks = (N + 15) / 16;               // 6250
    const int nAgg2Blocks = (N + 7) / 8;                 // 12500
    const int nTiles      = (N + 127) / 128;             // 782

    hipMemsetAsync(bcur, 0, NBUCKETS * 4, stream);
    wprep_kernel<<<20, 256, 0, stream>>>(W1, W2, W1f, W2f);

    bucket_scatter_kernel<<<nScatBlocks, 256, 0, stream>>>(src, dst, bcur, ebuf, E);
    bucket_sort_kernel<<<NBUCKETS, 256, 0, stream>>>(ebuf, bcur, ssrc, rs, cnt, dinv, N);

    gemm1_kernel<<<nTiles, 512, 0, stream>>>(x, W1f, dinv, (ushort*)h1, N);
    agg1f_kernel<<<nAgg1Blocks, 256, 0, stream>>>((const uint4*)h1, rs, cnt, ssrc, dinv, b1,
                                                  W2f, h2, N);
    agg2_kernel<<<nAgg2Blocks, 256, 0, stream>>>((const uint2*)h2, rs, cnt, ssrc, dinv, b2,
                                                 (float4*)out, N);
}

// Round 12
// 336.190 us; speedup vs baseline: 1.1235x; 1.0498x over previous
//
#include <hip/hip_runtime.h>
#include <hip/hip_bf16.h>

// GCN 2-layer: out = log_softmax(GCN2(relu(GCN1(x))))
// Round 19: pipeline concurrency via heterogeneous-block fusion.
// Chain was serial: scatter -> sort -> gemm1(needs dinv) -> agg1f -> agg2.
// (1) dinv moved OUT of gemm1 (raw xW1 in bf16); agg1f applies dinv[src]
// per edge via fmaf (same instr count; dinv L2-resident) and the
// self-loop becomes dn*(a + dn*h_n). gemm1 now independent of sort.
// (2) ONE dispatch runs scatter-blocks (0..390, first in dispatch order)
// and gemm1-blocks (391..1172) concurrently; 32-KB LDS union (role-split
// blocks never share). Scatter's ~40us hides under gemm1.
// Streams/events are banned under graph capture -- this gets the overlap
// with a plain single-stream launch.
// agg1f (gather at once-per-XCD L2-fill floor), agg2 v2, sort v2 frozen.

#define N_NODES 100000
#define F_IN 256
#define F_MID 128
#define F_OUT 64

#define BSHIFT 8                      // 256 nodes per bucket
#define BNODES 256
#define NBUCKETS ((N_NODES + BNODES - 1) / BNODES)   // 391
#define BCAP 6144                     // mean 4096, sigma ~64 -> +32 sigma
#define EPB 4096                      // edges per scatter block

typedef __attribute__((ext_vector_type(8))) short short8;
typedef __attribute__((ext_vector_type(4))) float f32x4;

__device__ inline ushort bf16_rne(float f) {
    uint u = __float_as_uint(f);
    u += 0x7FFF + ((u >> 16) & 1);
    return (ushort)(u >> 16);
}
__device__ inline float lo16(uint r) { return __uint_as_float(r << 16); }
__device__ inline float hi16(uint r) { return __uint_as_float(r & 0xffff0000u); }
__device__ inline uint pack_bf2(float a, float b) {
    return (uint)bf16_rne(a) | ((uint)bf16_rne(b) << 16);
}

// ---------------- S2: per-bucket counting sort (R17 v2) ----------------
__global__ __launch_bounds__(256)
void bucket_sort_kernel(const uint* __restrict__ ebuf, const int* __restrict__ bcur,
                        int* __restrict__ ssrc, int* __restrict__ rs, int* __restrict__ cnt,
                        float* __restrict__ dinv, int n) {
    __shared__ uint eL[BCAP];          // 24 KB
    __shared__ int  sLoc[BCAP];        // 24 KB sorted srcs
    __shared__ int hist[BNODES], ps[BNODES];
    int b = blockIdx.x, t = threadIdx.x;
    int nb = bcur[b];
    if (nb > BCAP) nb = BCAP;
    for (int i = t; i < nb; i += 256) eL[i] = ebuf[(size_t)b * BCAP + i];
    hist[t] = 0;
    __syncthreads();
    for (int i = t; i < nb; i += 256) atomicAdd(&hist[eL[i] >> 17], 1);
    __syncthreads();
    ps[t] = hist[t];
    __syncthreads();
#pragma unroll
    for (int off = 1; off < BNODES; off <<= 1) {
        int v = (t >= off) ? ps[t - off] : 0;
        __syncthreads();
        ps[t] += v;
        __syncthreads();
    }
    int excl = ps[t] - hist[t];
    int node = b * BNODES + t;
    if (node < n) {
        rs[node] = b * BCAP + excl;
        cnt[node] = hist[t];
        dinv[node] = 1.0f / sqrtf((float)hist[t] + 1.0f);
    }
    __syncthreads();
    ps[t] = excl;                      // reuse as running cursor
    __syncthreads();
    for (int i = t; i < nb; i += 256) {
        uint e = eL[i];
        int d = e >> 17;
        int p = atomicAdd(&ps[d], 1);
        sLoc[p] = (int)(e & 0x1FFFF);
    }
    __syncthreads();
    for (int i = t; i < nb; i += 256) ssrc[(size_t)b * BCAP + i] = sLoc[i];
}

// ---------------- weight prep: fragment-ordered bf16 ----------------
__global__ __launch_bounds__(256)
void wprep_kernel(const float* __restrict__ W1, const float* __restrict__ W2,
                  short8* __restrict__ W1f, short8* __restrict__ W2f) {
    int b = blockIdx.x;
    if (b < 16) {
        int f = b * 256 + threadIdx.x;
        int k0 = f >> 9, nt = (f >> 6) & 7, ln = f & 63;
        int kbase = k0 * 32 + (ln >> 4) * 8;
        int n = nt * 16 + (ln & 15);
        short8 fr;
#pragma unroll
        for (int j = 0; j < 8; ++j) fr[j] = (short)bf16_rne(W1[(kbase + j) * F_MID + n]);
        W1f[f] = fr;
    } else {
        int f = (b - 16) * 256 + threadIdx.x;
        int k0 = f >> 8, nt = (f >> 6) & 3, ln = f & 63;
        int kbase = k0 * 32 + (ln >> 4) * 8;
        int n = nt * 16 + (ln & 15);
        short8 fr;
#pragma unroll
        for (int j = 0; j < 8; ++j) fr[j] = (short)bf16_rne(W2[(kbase + j) * F_OUT + n]);
        W2f[f] = fr;
    }
}

// ---------------- fused scatter + gemm1 (heterogeneous blocks) ----------------
// Blocks [0, nScat): S1 bucket scatter (512-thread variant of R17 v2).
// Blocks [nScat, nScat+nTiles): gemm1 tile (R18 v3, raw xW1 -- no dinv).
// 32-KB LDS union: scatter tables (31.5 KB) / gemm1 A-dbuf (32 KB).
__global__ __launch_bounds__(512, 4)
void sg_kernel(const int* __restrict__ src, const int* __restrict__ dst,
               int* __restrict__ bcur, uint* __restrict__ ebuf, int E,
               const float* __restrict__ A, const short8* __restrict__ Wf,
               ushort* __restrict__ C, int M, int nScat) {
    __shared__ __align__(16) char smemRaw[32768];
    int t = threadIdx.x;

    if ((int)blockIdx.x < nScat) {
        // ---- scatter role ----
        int* hist = (int*)smemRaw;             // 512 ints
        int* ps   = hist + 512;                // 512 ints
        int* cur  = ps + 512;                  // 512 ints
        int* base = cur + 512;                 // NBUCKETS ints
        uint*   eLoc = (uint*)(base + NBUCKETS);   // EPB uints
        ushort* bLoc = (ushort*)(eLoc + EPB);      // EPB ushorts

        int e0 = blockIdx.x * EPB;
        int e1 = e0 + EPB; if (e1 > E) e1 = E;
        int ne = e1 - e0;

        hist[t] = 0;
        __syncthreads();
        for (int i = t; i < ne; i += 512) atomicAdd(&hist[dst[e0 + i] >> BSHIFT], 1);
        __syncthreads();
        ps[t] = hist[t];
        __syncthreads();
#pragma unroll
        for (int off = 1; off < 512; off <<= 1) {
            int v = (t >= off) ? ps[t - off] : 0;
            __syncthreads();
            ps[t] += v;
            __syncthreads();
        }
        int ex = ps[t] - hist[t];
        ps[t] = ex; cur[t] = ex;
        __syncthreads();
        for (int i = t; i < ne; i += 512) {
            int d = dst[e0 + i], s = src[e0 + i];
            int b = d >> BSHIFT;
            int p = atomicAdd(&cur[b], 1);
            eLoc[p] = ((uint)(d & (BNODES - 1)) << 17) | (uint)s;
            bLoc[p] = (ushort)b;
        }
        __syncthreads();
        for (int b = t; b < NBUCKETS; b += 512) {
            int h = hist[b];
            base[b] = h ? atomicAdd(&bcur[b], h) : 0;
        }
        __syncthreads();
        for (int i = t; i < ne; i += 512) {
            int b = bLoc[i];
            int d = base[b] + (i - ps[b]);
            if (d < BCAP) ebuf[(size_t)b * BCAP + d] = eLoc[i];
        }
        return;
    }

    // ---- gemm1 role: h1[M,128](bf16) = x[M,256](fp32) @ W1bf16 (raw) ----
    ushort* Ab = (ushort*)smemRaw;            // [2][128*64]
    int lane = t & 63, w = t >> 6;            // w in 0..7
    int bx = blockIdx.x - nScat;
    int m0 = bx * 128;

    int o0 = t * 2;
    int srow = o0 >> 3;
    int gr = m0 + srow; if (gr >= M) gr = m0;
    int cl0 = o0 & 7, cl1 = cl0 + 1;
    int cg0 = cl0 ^ (srow & 7), cg1 = cl1 ^ (srow & 7);
    const float* arow = &A[(size_t)gr * F_IN];

    float4 rv[2][2];
    rv[0][0] = ((const float4*)(arow + cg0 * 8))[0];
    rv[0][1] = ((const float4*)(arow + cg0 * 8))[1];
    rv[1][0] = ((const float4*)(arow + cg1 * 8))[0];
    rv[1][1] = ((const float4*)(arow + cg1 * 8))[1];

    {
        short8 pk;
        pk[0] = (short)bf16_rne(rv[0][0].x); pk[1] = (short)bf16_rne(rv[0][0].y);
        pk[2] = (short)bf16_rne(rv[0][0].z); pk[3] = (short)bf16_rne(rv[0][0].w);
        pk[4] = (short)bf16_rne(rv[0][1].x); pk[5] = (short)bf16_rne(rv[0][1].y);
        pk[6] = (short)bf16_rne(rv[0][1].z); pk[7] = (short)bf16_rne(rv[0][1].w);
        *(short8*)&Ab[o0 * 8] = pk;
        pk[0] = (short)bf16_rne(rv[1][0].x); pk[1] = (short)bf16_rne(rv[1][0].y);
        pk[2] = (short)bf16_rne(rv[1][0].z); pk[3] = (short)bf16_rne(rv[1][0].w);
        pk[4] = (short)bf16_rne(rv[1][1].x); pk[5] = (short)bf16_rne(rv[1][1].y);
        pk[6] = (short)bf16_rne(rv[1][1].z); pk[7] = (short)bf16_rne(rv[1][1].w);
        *(short8*)&Ab[(o0 + 1) * 8] = pk;
    }
    __syncthreads();

    f32x4 acc[8];
#pragma unroll
    for (int nt = 0; nt < 8; ++nt) acc[nt] = (f32x4){0.f, 0.f, 0.f, 0.f};

    int arow16 = w * 16 + (lane & 15);
    int asw = arow16 & 7;
    int abase = arow16 * 8;

#pragma unroll
    for (int kc = 0; kc < 4; ++kc) {
        int b = kc & 1;
        if (kc < 3) {
            const float* s0 = arow + (kc + 1) * 64 + cg0 * 8;
            const float* s1 = arow + (kc + 1) * 64 + cg1 * 8;
            rv[0][0] = ((const float4*)s0)[0];
            rv[0][1] = ((const float4*)s0)[1];
            rv[1][0] = ((const float4*)s1)[0];
            rv[1][1] = ((const float4*)s1)[1];
            asm volatile("" ::: "memory");
        }
#pragma unroll
        for (int kk = 0; kk < 2; ++kk) {
            int k0 = kc * 2 + kk;
            int c = kk * 4 + (lane >> 4);
            short8 af = *(const short8*)&Ab[b * 8192 + (abase + (c ^ asw)) * 8];
#pragma unroll
            for (int nt = 0; nt < 8; ++nt) {
                short8 bfr = Wf[(k0 * 8 + nt) * 64 + lane];   // L2-hit read
                acc[nt] = __builtin_amdgcn_mfma_f32_16x16x32_bf16(af, bfr, acc[nt], 0, 0, 0);
            }
        }
        if (kc < 3) {
            short8 pk;
            pk[0] = (short)bf16_rne(rv[0][0].x); pk[1] = (short)bf16_rne(rv[0][0].y);
            pk[2] = (short)bf16_rne(rv[0][0].z); pk[3] = (short)bf16_rne(rv[0][0].w);
            pk[4] = (short)bf16_rne(rv[0][1].x); pk[5] = (short)bf16_rne(rv[0][1].y);
            pk[6] = (short)bf16_rne(rv[0][1].z); pk[7] = (short)bf16_rne(rv[0][1].w);
            *(short8*)&Ab[(b ^ 1) * 8192 + o0 * 8] = pk;
            pk[0] = (short)bf16_rne(rv[1][0].x); pk[1] = (short)bf16_rne(rv[1][0].y);
            pk[2] = (short)bf16_rne(rv[1][0].z); pk[3] = (short)bf16_rne(rv[1][0].w);
            pk[4] = (short)bf16_rne(rv[1][1].x); pk[5] = (short)bf16_rne(rv[1][1].y);
            pk[6] = (short)bf16_rne(rv[1][1].z); pk[7] = (short)bf16_rne(rv[1][1].w);
            *(short8*)&Ab[(b ^ 1) * 8192 + (o0 + 1) * 8] = pk;
        }
        __syncthreads();
    }

#pragma unroll
    for (int i = 0; i < 4; ++i) {
        int r = m0 + w * 16 + (lane >> 4) * 4 + i;
        if (r < M) {
#pragma unroll
            for (int nt = 0; nt < 8; ++nt)
                C[(size_t)r * F_MID + nt * 16 + (lane & 15)] = bf16_rne(acc[nt][i]);
        }
    }
}

// ---------------- fused aggregation-1 + gemm2 ----------------
// h1 rows are RAW xW1; per-edge weight dinv[src] applied via fmaf; self
// term dn*(a + dn*h_n). Phase 2 (h2 = dinv*(h1a@W2)) unchanged.
__global__ __launch_bounds__(256)
void agg1f_kernel(const uint4* __restrict__ h, const int* __restrict__ rs,
                  const int* __restrict__ cnt, const int* __restrict__ ssrc,
                  const float* __restrict__ dinv, const float* __restrict__ bias,
                  const short8* __restrict__ W2f, ushort* __restrict__ h2, int n) {
    __shared__ __align__(16) ushort rowsL[16][136];   // 16 rows x 128 bf16 + pad
    int w = threadIdx.x >> 6, lane = threadIdx.x & 63;
    int q = lane >> 4, c16 = lane & 15;
    int nbase = blockIdx.x * 16;
    const float4* b4 = (const float4*)bias;
    float4 b0 = b4[c16 * 2], b1v = b4[c16 * 2 + 1];

#pragma unroll
    for (int i = 0; i < 4; ++i) {
        int node = nbase + w * 4 + i;
        bool nOk = (node < n);
        int start = nOk ? rs[node] : 0;
        int c = nOk ? cnt[node] : 0;
        float dn = nOk ? dinv[node] : 0.f;
        float a[8];
#pragma unroll
        for (int k = 0; k < 8; ++k) a[k] = 0.f;

        for (int base = 0; base < c; base += 16) {
            bool p[4];
            int s[4];
            float ds[4];
            uint4 r[4];
#pragma unroll
            for (int j = 0; j < 4; ++j) {
                int e = base + j * 4 + q;
                p[j] = e < c;
                if (p[j]) s[j] = ssrc[start + e];
            }
#pragma unroll
            for (int j = 0; j < 4; ++j) {
                if (p[j]) {
                    r[j] = h[(size_t)s[j] * 16 + c16];
                    ds[j] = dinv[s[j]];
                }
            }
#pragma unroll
            for (int j = 0; j < 4; ++j) {
                if (p[j]) {
                    a[0] = fmaf(ds[j], lo16(r[j].x), a[0]); a[1] = fmaf(ds[j], hi16(r[j].x), a[1]);
                    a[2] = fmaf(ds[j], lo16(r[j].y), a[2]); a[3] = fmaf(ds[j], hi16(r[j].y), a[3]);
                    a[4] = fmaf(ds[j], lo16(r[j].z), a[4]); a[5] = fmaf(ds[j], hi16(r[j].z), a[5]);
                    a[6] = fmaf(ds[j], lo16(r[j].w), a[6]); a[7] = fmaf(ds[j], hi16(r[j].w), a[7]);
                }
            }
        }
#pragma unroll
        for (int k = 0; k < 8; ++k) {
            a[k] += __shfl_xor(a[k], 16);
            a[k] += __shfl_xor(a[k], 32);
        }
        if (q == 0) {
            short8 pk;
            if (nOk) {
                uint4 sr = h[(size_t)node * 16 + c16];
                float o0 = fmaxf(fmaf(dn, fmaf(dn, lo16(sr.x), a[0]), b0.x), 0.f);
                float o1 = fmaxf(fmaf(dn, fmaf(dn, hi16(sr.x), a[1]), b0.y), 0.f);
                float o2 = fmaxf(fmaf(dn, fmaf(dn, lo16(sr.y), a[2]), b0.z), 0.f);
                float o3 = fmaxf(fmaf(dn, fmaf(dn, hi16(sr.y), a[3]), b0.w), 0.f);
                float o4 = fmaxf(fmaf(dn, fmaf(dn, lo16(sr.z), a[4]), b1v.x), 0.f);
                float o5 = fmaxf(fmaf(dn, fmaf(dn, hi16(sr.z), a[5]), b1v.y), 0.f);
                float o6 = fmaxf(fmaf(dn, fmaf(dn, lo16(sr.w), a[6]), b1v.z), 0.f);
                float o7 = fmaxf(fmaf(dn, fmaf(dn, hi16(sr.w), a[7]), b1v.w), 0.f);
                pk[0] = (short)bf16_rne(o0); pk[1] = (short)bf16_rne(o1);
                pk[2] = (short)bf16_rne(o2); pk[3] = (short)bf16_rne(o3);
                pk[4] = (short)bf16_rne(o4); pk[5] = (short)bf16_rne(o5);
                pk[6] = (short)bf16_rne(o6); pk[7] = (short)bf16_rne(o7);
            } else {
                pk = (short8){0, 0, 0, 0, 0, 0, 0, 0};
            }
            *(short8*)&rowsL[w * 4 + i][c16 * 8] = pk;
        }
    }
    __syncthreads();

    // phase 2: wave w -> col-tile nt=w.
    f32x4 acc = (f32x4){0.f, 0.f, 0.f, 0.f};
    int ar = lane & 15;
#pragma unroll
    for (int k0 = 0; k0 < 4; ++k0) {
        short8 af = *(const short8*)&rowsL[ar][k0 * 32 + (lane >> 4) * 8];
        short8 bfr = W2f[(k0 * 4 + w) * 64 + lane];
        acc = __builtin_amdgcn_mfma_f32_16x16x32_bf16(af, bfr, acc, 0, 0, 0);
    }
#pragma unroll
    for (int i = 0; i < 4; ++i) {
        int r = (lane >> 4) * 4 + i;
        int node = nbase + r;
        if (node < n) {
            float dv = dinv[node];
            h2[(size_t)node * F_OUT + w * 16 + (lane & 15)] = bf16_rne(dv * acc[i]);
        }
    }
}

// agg2 v2: 2 nodes/wave, interleaved x4-unrolled gathers; fused log_softmax.
__global__ __launch_bounds__(256)
void agg2_kernel(const uint2* __restrict__ h, const int* __restrict__ rs,
                 const int* __restrict__ cnt, const int* __restrict__ ssrc,
                 const float* __restrict__ dinv, const float* __restrict__ bias,
                 float4* __restrict__ out4, int n) {
    int w = threadIdx.x >> 6, lane = threadIdx.x & 63;
    int q = lane >> 4, c16 = lane & 15;
    int nodeA = blockIdx.x * 8 + w * 2;
    int nodeB = nodeA + 1;
    bool okA = (nodeA < n), okB = (nodeB < n);
    if (!okA) return;
    int startA = rs[nodeA], cA = cnt[nodeA];
    int startB = okB ? rs[nodeB] : 0, cB = okB ? cnt[nodeB] : 0;
    float dnA = dinv[nodeA];
    float dnB = okB ? dinv[nodeB] : 0.f;
    float aA[4], aB[4];
#pragma unroll
    for (int i = 0; i < 4; ++i) { aA[i] = 0.f; aB[i] = 0.f; }

    int cm = cA > cB ? cA : cB;
    for (int base = 0; base < cm; base += 16) {
        bool pA[4], pB[4];
        int sA[4], sB[4];
        uint2 rA[4], rB[4];
#pragma unroll
        for (int j = 0; j < 4; ++j) {
            int e = base + j * 4 + q;
            pA[j] = e < cA;
            pB[j] = e < cB;
            if (pA[j]) sA[j] = ssrc[startA + e];
            if (pB[j]) sB[j] = ssrc[startB + e];
        }
#pragma unroll
        for (int j = 0; j < 4; ++j) {
            if (pA[j]) rA[j] = h[(size_t)sA[j] * 16 + c16];
            if (pB[j]) rB[j] = h[(size_t)sB[j] * 16 + c16];
        }
#pragma unroll
        for (int j = 0; j < 4; ++j) {
            if (pA[j]) {
                aA[0] += lo16(rA[j].x); aA[1] += hi16(rA[j].x);
                aA[2] += lo16(rA[j].y); aA[3] += hi16(rA[j].y);
            }
            if (pB[j]) {
                aB[0] += lo16(rB[j].x); aB[1] += hi16(rB[j].x);
                aB[2] += lo16(rB[j].y); aB[3] += hi16(rB[j].y);
            }
        }
    }
#pragma unroll
    for (int i = 0; i < 4; ++i) {
        aA[i] += __shfl_xor(aA[i], 16);
        aA[i] += __shfl_xor(aA[i], 32);
        aB[i] += __shfl_xor(aB[i], 16);
        aB[i] += __shfl_xor(aB[i], 32);
    }
    float4 bv = ((const float4*)bias)[c16];
    {
        uint2 sr = h[(size_t)nodeA * 16 + c16];
        float v0 = fmaf(dnA, aA[0] + lo16(sr.x), bv.x);
        float v1 = fmaf(dnA, aA[1] + hi16(sr.x), bv.y);
        float v2 = fmaf(dnA, aA[2] + lo16(sr.y), bv.z);
        float v3 = fmaf(dnA, aA[3] + hi16(sr.y), bv.w);
        float m = fmaxf(fmaxf(v0, v1), fmaxf(v2, v3));
#pragma unroll
        for (int off = 1; off < 16; off <<= 1) m = fmaxf(m, __shfl_xor(m, off));
        float ssum = expf(v0 - m) + expf(v1 - m) + expf(v2 - m) + expf(v3 - m);
#pragma unroll
        for (int off = 1; off < 16; off <<= 1) ssum += __shfl_xor(ssum, off);
        float lg = m + logf(ssum);
        if (q == 0) out4[(size_t)nodeA * 16 + c16] = make_float4(v0 - lg, v1 - lg, v2 - lg, v3 - lg);
    }
    if (okB) {
        uint2 sr = h[(size_t)nodeB * 16 + c16];
        float v0 = fmaf(dnB, aB[0] + lo16(sr.x), bv.x);
        float v1 = fmaf(dnB, aB[1] + hi16(sr.x), bv.y);
        float v2 = fmaf(dnB, aB[2] + lo16(sr.y), bv.z);
        float v3 = fmaf(dnB, aB[3] + hi16(sr.y), bv.w);
        float m = fmaxf(fmaxf(v0, v1), fmaxf(v2, v3));
#pragma unroll
        for (int off = 1; off < 16; off <<= 1) m = fmaxf(m, __shfl_xor(m, off));
        float ssum = expf(v0 - m) + expf(v1 - m) + expf(v2 - m) + expf(v3 - m);
#pragma unroll
        for (int off = 1; off < 16; off <<= 1) ssum += __shfl_xor(ssum, off);
        float lg = m + logf(ssum);
        if (q == 0) out4[(size_t)nodeB * 16 + c16] = make_float4(v0 - lg, v1 - lg, v2 - lg, v3 - lg);
    }
}

// ---------------- launch ----------------

extern "C" void kernel_launch(void* const* d_in, const int* in_sizes, int n_in,
                              void* d_out, int out_size, void* d_ws, size_t ws_size,
                              hipStream_t stream) {
    const float* x  = (const float*)d_in[0];
    const int*   ei = (const int*)d_in[1];
    const float* W1 = (const float*)d_in[2];
    const float* b1 = (const float*)d_in[3];
    const float* W2 = (const float*)d_in[4];
    const float* b2 = (const float*)d_in[5];
    float* out = (float*)d_out;

    const int N = N_NODES;
    const int E = in_sizes[1] / 2;
    const int* src = ei;
    const int* dst = ei + E;

    char* ws = (char*)d_ws;
    size_t off = 0;
    auto alloc = [&](size_t bytes) {
        char* p = ws + off;
        off = (off + bytes + 255) & ~(size_t)255;
        return p;
    };
    int*    bcur   = (int*)alloc(NBUCKETS * 4);
    int*    rs     = (int*)alloc(N * 4);
    int*    cnt    = (int*)alloc(N * 4);
    float*  dinv   = (float*)alloc(N * 4);
    short8* W1f    = (short8*)alloc(4096 * 16);
    short8* W2f    = (short8*)alloc(1024 * 16);
    uint*   ebuf   = (uint*)alloc((size_t)NBUCKETS * BCAP * 4);   // 9.6 MB
    int*    ssrc   = (int*)alloc((size_t)NBUCKETS * BCAP * 4);    // 9.6 MB
    uint*   h1     = (uint*)alloc((size_t)N * 64 * 4);            // 128 bf16/row
    ushort* h2     = (ushort*)alloc((size_t)N * 64 * 2);          // 64 bf16/row

    const int nScat       = (E + EPB - 1) / EPB;         // 391
    const int nAgg1Blocks = (N + 15) / 16;               // 6250
    const int nAgg2Blocks = (N + 7) / 8;                 // 12500
    const int nTiles      = (N + 127) / 128;             // 782

    hipMemsetAsync(bcur, 0, NBUCKETS * 4, stream);
    wprep_kernel<<<20, 256, 0, stream>>>(W1, W2, W1f, W2f);

    sg_kernel<<<nScat + nTiles, 512, 0, stream>>>(src, dst, bcur, ebuf, E,
                                                  x, W1f, (ushort*)h1, N, nScat);
    bucket_sort_kernel<<<NBUCKETS, 256, 0, stream>>>(ebuf, bcur, ssrc, rs, cnt, dinv, N);

    agg1f_kernel<<<nAgg1Blocks, 256, 0, stream>>>((const uint4*)h1, rs, cnt, ssrc, dinv, b1,
                                                  W2f, h2, N);
    agg2_kernel<<<nAgg2Blocks, 256, 0, stream>>>((const uint2*)h2, rs, cnt, ssrc, dinv, b2,
                                                 (float4*)out, N);
}